// Round 10
// baseline (689.718 us; speedup 1.0000x reference)
//
#include <hip/hip_runtime.h>
#include <hip/hip_bf16.h>

typedef __bf16 bf16x8 __attribute__((ext_vector_type(8)));
typedef float  f32x4  __attribute__((ext_vector_type(4)));

#define BN_EPS 1e-5f

// Per-image activation bytes (NHWC, padded 30x30):
constexpr size_t ACT_PER_IMG = 57600 + 115200 + 230400;      // 403200
constexpr size_t SZ_POOL = (size_t)1024 * 128 * 4;
constexpr size_t SZ_W2   = (size_t)9 * 64 * 32 * 2;
constexpr size_t SZ_W3   = (size_t)9 * 128 * 64 * 2;
constexpr size_t SZ_W4   = (size_t)9 * 128 * 128 * 2;
constexpr size_t SZ_BN   = 704 * 4;
constexpr size_t SZ_FIXED = SZ_POOL + SZ_W2 + SZ_W3 + SZ_W4 + SZ_BN;

__device__ __forceinline__ unsigned pack2(float a, float b) {
    __hip_bfloat162 h = __float22bfloat162_rn(make_float2(a, b));
    union { __hip_bfloat162 h2; unsigned u; } u;
    u.h2 = h;
    return u.u;
}

// ---------------- prep: weight transform to MFMA-fragment order + BN fold ----
// Fragment order: W'[s][nb][lane][e], s = t*KC + kc (K-step), nb = n-block of 16,
// lane in [0,64), e in [0,8). Element = w[o][i][t] with o = nb*16 + (lane&15),
// i = kc*32 + (lane>>4)*8 + e. A wave's B-fragment load is 64 lanes x 16B
// CONTIGUOUS (1KB) -> coalesced (this fixed the r6-r8 VMEM-scatter bottleneck).
struct PrepArgs {
    const float *w2, *w3, *w4;
    const float *g1, *b1, *m1, *v1;
    const float *g2, *b2, *m2, *v2;
    const float *g3, *b3, *m3, *v3;
    const float *g4, *b4, *m4, *v4;
    __hip_bfloat16 *W2, *W3, *W4;
    float *bn;
};

__global__ __launch_bounds__(256) void prep_k(PrepArgs a) {
    int idx = blockIdx.x * 256 + threadIdx.x;
    if (idx < 18432) {            // W2: CIN=32 (KC=1), COUT=64 (NB=4)
        int e = idx & 7, lane = (idx >> 3) & 63, r = idx >> 9;   // r: 0..35
        int nb = r & 3, t = r >> 2;                              // kc = 0
        int o = nb * 16 + (lane & 15);
        int i = (lane >> 4) * 8 + e;
        a.W2[idx] = __float2bfloat16(a.w2[(o * 32 + i) * 9 + t]);
        return;
    }
    idx -= 18432;
    if (idx < 73728) {            // W3: CIN=64 (KC=2), COUT=128 (NB=8)
        int e = idx & 7, lane = (idx >> 3) & 63, r = idx >> 9;   // r: 0..143
        int nb = r & 7, s = r >> 3;                              // s: 0..17
        int kc = s & 1, t = s >> 1;
        int o = nb * 16 + (lane & 15);
        int i = kc * 32 + (lane >> 4) * 8 + e;
        a.W3[idx] = __float2bfloat16(a.w3[(o * 64 + i) * 9 + t]);
        return;
    }
    idx -= 73728;
    if (idx < 147456) {           // W4: CIN=128 (KC=4), COUT=128 (NB=8)
        int e = idx & 7, lane = (idx >> 3) & 63, r = idx >> 9;   // r: 0..287
        int nb = r & 7, s = r >> 3;                              // s: 0..35
        int kc = s & 3, t = s >> 2;
        int o = nb * 16 + (lane & 15);
        int i = kc * 32 + (lane >> 4) * 8 + e;
        a.W4[idx] = __float2bfloat16(a.w4[(o * 128 + i) * 9 + t]);
        return;
    }
    idx -= 147456;
    if (idx < 352) {
        const float *g, *bb, *mm, *vv; int c, so, cn;
        if (idx < 32)       { g = a.g1; bb = a.b1; mm = a.m1; vv = a.v1; c = idx;       so = 0;   cn = 32;  }
        else if (idx < 96)  { g = a.g2; bb = a.b2; mm = a.m2; vv = a.v2; c = idx - 32;  so = 64;  cn = 64;  }
        else if (idx < 224) { g = a.g3; bb = a.b3; mm = a.m3; vv = a.v3; c = idx - 96;  so = 192; cn = 128; }
        else                { g = a.g4; bb = a.b4; mm = a.m4; vv = a.v4; c = idx - 224; so = 448; cn = 128; }
        float s = g[c] * rsqrtf(vv[c] + BN_EPS);
        a.bn[so + c] = s;
        a.bn[so + cn + c] = bb[c] - mm[c] * s;
    }
}

// ---------------- kernel 1: offsets + deform sample + DCN + BN1 ----------------
__global__ __launch_bounds__(256) void deform_k(
    const float* __restrict__ x, const float* __restrict__ w_off,
    const float* __restrict__ b_off, const float* __restrict__ w_dcn,
    const float* __restrict__ b_dcn, const float* __restrict__ bn,
    __hip_bfloat16* __restrict__ act1, __hip_bfloat16* __restrict__ act2,
    __hip_bfloat16* __restrict__ act3, float* __restrict__ pooled, int b0)
{
    const int lb = blockIdx.x;
    const int b  = b0 + lb;
    const int tid = threadIdx.x;
    __shared__ float xp[900];
    __shared__ float sw[564];
    float* swo = sw;
    float* sbo = sw + 162;
    float* swd = sw + 180;
    float* sbd = sw + 468;
    float* ss1 = sw + 500;
    float* ssh = sw + 532;

    for (int i = tid; i < 900; i += 256) {
        int y = i / 30, xc = i % 30;
        float v = 0.f;
        if (y >= 1 && y <= 28 && xc >= 1 && xc <= 28)
            v = x[(size_t)b * 784 + (y - 1) * 28 + (xc - 1)];
        xp[i] = v;
    }
    for (int i = tid; i < 564; i += 256) {
        float v;
        if (i < 162)      v = w_off[i];
        else if (i < 180) v = b_off[i - 162];
        else if (i < 468) v = w_dcn[i - 180];
        else if (i < 500) v = b_dcn[i - 468];
        else if (i < 532) v = bn[i - 500];
        else              v = bn[32 + (i - 532)];
        sw[i] = v;
    }
    if (tid < 128) pooled[b * 128 + tid] = 0.f;
    __syncthreads();

    for (int p = tid; p < 784; p += 256) {
        int y = p / 28, xx = p % 28;
        float off[18];
        #pragma unroll
        for (int o = 0; o < 18; o++) off[o] = sbo[o];
        #pragma unroll
        for (int ty = 0; ty < 3; ty++)
            #pragma unroll
            for (int tx = 0; tx < 3; tx++) {
                float xv = xp[(y + ty) * 30 + (xx + tx)];
                int tap = ty * 3 + tx;
                #pragma unroll
                for (int o = 0; o < 18; o++) off[o] = fmaf(xv, swo[o * 9 + tap], off[o]);
            }
        float s[9];
        #pragma unroll
        for (int j = 0; j < 9; j++) {
            float py = (float)y + (float)(j / 3 - 1) + off[2 * j];
            float px = (float)xx + (float)(j % 3 - 1) + off[2 * j + 1];
            float y0 = floorf(py), x0 = floorf(px);
            float wy1 = py - y0, wx1 = px - x0;
            float wy0 = 1.f - wy1, wx0 = 1.f - wx1;
            float acc = 0.f;
            #pragma unroll
            for (int cy = 0; cy < 2; cy++)
                #pragma unroll
                for (int cx = 0; cx < 2; cx++) {
                    float yy = y0 + (float)cy, xf = x0 + (float)cx;
                    bool valid = (yy >= 0.f) && (yy <= 27.f) && (xf >= 0.f) && (xf <= 27.f);
                    int yc = (int)fminf(fmaxf(yy, 0.f), 27.f);
                    int xc = (int)fminf(fmaxf(xf, 0.f), 27.f);
                    float g = valid ? xp[(yc + 1) * 30 + (xc + 1)] : 0.f;
                    float w = (cy ? wy1 : wy0) * (cx ? wx1 : wx0);
                    acc = fmaf(g, w, acc);
                }
            s[j] = acc;
        }
        size_t base = ((size_t)lb * 900 + (size_t)(y + 1) * 30 + (xx + 1)) * 32;
        #pragma unroll
        for (int c0 = 0; c0 < 32; c0 += 8) {
            float h[8];
            #pragma unroll
            for (int ci = 0; ci < 8; ci++) {
                int c = c0 + ci;
                float hv = sbd[c];
                #pragma unroll
                for (int j = 0; j < 9; j++) hv = fmaf(s[j], swd[c * 9 + j], hv);
                h[ci] = hv * ss1[c] + ssh[c];
            }
            uint4 q;
            q.x = pack2(h[0], h[1]); q.y = pack2(h[2], h[3]);
            q.z = pack2(h[4], h[5]); q.w = pack2(h[6], h[7]);
            *reinterpret_cast<uint4*>(&act1[base + c0]) = q;
        }
    }

    for (int i = tid; i < 116; i += 256) {
        int py, px;
        if (i < 30)      { py = 0;          px = i; }
        else if (i < 60) { py = 29;         px = i - 30; }
        else if (i < 88) { py = i - 60 + 1; px = 0; }
        else             { py = i - 88 + 1; px = 29; }
        size_t pix = (size_t)lb * 900 + (size_t)py * 30 + px;
        uint4 z = {0, 0, 0, 0};
        uint4* p1 = reinterpret_cast<uint4*>(&act1[pix * 32]);
        #pragma unroll
        for (int k = 0; k < 4; k++) p1[k] = z;
        uint4* p2 = reinterpret_cast<uint4*>(&act2[pix * 64]);
        #pragma unroll
        for (int k = 0; k < 8; k++) p2[k] = z;
        uint4* p3 = reinterpret_cast<uint4*>(&act3[pix * 128]);
        #pragma unroll
        for (int k = 0; k < 16; k++) p3[k] = z;
    }
}

// ---------------- conv 3x3 (implicit GEMM, MFMA bf16, 4-wave NFW=COUT/32) ----
template<int CIN>
__device__ __forceinline__ int swz(int ofs) {
    if constexpr (CIN == 128) return (ofs >> 4) & 0x70;      // bits 8-10 -> 4-6
    else if constexpr (CIN == 64) return (ofs >> 3) & 0x70;  // bits 7-9  -> 4-6
    else return (ofs >> 2) & 0x30;                           // bits 6-7  -> 4-5
}

// Weight fragment load, fragment-order layout: contiguous 1KB per frag per wave.
template<int COUT, int NFW>
__device__ __forceinline__ void loadWf(const __hip_bfloat16* __restrict__ Wt,
                                       int s, int nhalf, int lane, bf16x8 (&bf)[NFW]) {
    constexpr int NB = COUT / 16;
    #pragma unroll
    for (int nf = 0; nf < NFW; ++nf)
        bf[nf] = *reinterpret_cast<const bf16x8*>(
            Wt + (((size_t)s * NB + nhalf * NFW + nf) * 64 + lane) * 8);
}

template<int CIN, int MFW>
__device__ __forceinline__ void loadAf(const __hip_bfloat16* tile,
                                       int s, const int (&pr)[4], const int (&pc)[4],
                                       int kg, bf16x8 (&af)[MFW]) {
    constexpr int KC = CIN / 32;
    int t = s / KC, kc = (s % KC) * 32;
    int ty = t / 3, tx = t % 3;
    #pragma unroll
    for (int mf = 0; mf < MFW; ++mf) {
        int pix = (pr[mf] + ty) * 30 + (pc[mf] + tx);
        int ba = (pix * CIN + kc + kg * 8) * 2;
        ba ^= swz<CIN>(ba);
        af[mf] = *reinterpret_cast<const bf16x8*>(
            reinterpret_cast<const char*>(tile) + ba);
    }
}

template<int MFW, int NFW>
__device__ __forceinline__ void mstep(const bf16x8 (&af)[MFW], const bf16x8 (&wf)[NFW],
                                      f32x4 (&acc)[MFW][NFW]) {
    #pragma unroll
    for (int mf = 0; mf < MFW; ++mf)
        #pragma unroll
        for (int nf = 0; nf < NFW; ++nf)
            acc[mf][nf] = __builtin_amdgcn_mfma_f32_16x16x32_bf16(
                af[mf], wf[nf], acc[mf][nf], 0, 0, 0);
}

// 4 waves per block: wave = (mhalf 0..1) x (nhalf 0..1). Each wave: MFW m-frags,
// NFW = COUT/32 n-frags (nhalf picks the half of COUT). Each A-read feeds NFW
// MFMAs -> halves LDS-pipe demand vs the 8-wave NFW/2 split (r9's limiter).
template<int CIN, int COUT, bool POOL, int MFW>
__device__ __forceinline__ void conv_body(
    const __hip_bfloat16* tile,
    const __hip_bfloat16* __restrict__ Wt,
    const float* __restrict__ bconv, const float* __restrict__ bnS,
    const float* __restrict__ bnB, __hip_bfloat16* __restrict__ aout,
    float* __restrict__ pooled, int lb, int gb, int rg, int lane, int mhalf, int nhalf)
{
    constexpr int KC  = CIN / 32;
    constexpr int NS  = 9 * KC;
    constexpr int NFW = COUT / 32;
    const int l15 = lane & 15, kg = lane >> 4;
    const int nbase = nhalf * (NFW * 16) + l15;

    int pr[4], pc[4];
    #pragma unroll
    for (int mf = 0; mf < MFW; ++mf) {
        int m = (mhalf * 4 + mf) * 16 + l15;
        pr[mf] = m / 28;
        pc[mf] = m % 28;
    }

    f32x4 acc[MFW][NFW] = {};
    bf16x8 w0[NFW], w1[NFW], a0[MFW];

    // weights double-buffered one K-step ahead
    loadWf<COUT, NFW>(Wt, 0, nhalf, lane, w0);
    #pragma unroll
    for (int s = 0; s < NS; s += 2) {
        loadAf<CIN, MFW>(tile, s, pr, pc, kg, a0);
        if (s + 1 < NS) loadWf<COUT, NFW>(Wt, s + 1, nhalf, lane, w1);
        mstep<MFW, NFW>(a0, w0, acc);
        if (s + 1 < NS) {
            loadAf<CIN, MFW>(tile, s + 1, pr, pc, kg, a0);
            if (s + 2 < NS) loadWf<COUT, NFW>(Wt, s + 2, nhalf, lane, w0);
            mstep<MFW, NFW>(a0, w1, acc);
        }
    }

    if constexpr (!POOL) {
        #pragma unroll
        for (int mf = 0; mf < MFW; ++mf) {
            #pragma unroll
            for (int nf = 0; nf < NFW; ++nf) {
                int n = nbase + nf * 16;
                float bc = bconv[n], sc = bnS[n], sh = bnB[n];
                #pragma unroll
                for (int r = 0; r < 4; r++) {
                    int m = (mhalf * 4 + mf) * 16 + kg * 4 + r;
                    float y = acc[mf][nf][r] + bc;
                    y = fmaxf(y, 0.f);
                    y = y * sc + sh;
                    int oy = m / 28, ox = m % 28;
                    aout[((size_t)lb * 900 + (size_t)(rg * 4 + oy + 1) * 30 + (ox + 1)) * COUT + n]
                        = __float2bfloat16(y);
                }
            }
        }
    } else {
        #pragma unroll
        for (int nf = 0; nf < NFW; ++nf) {
            int n = nbase + nf * 16;
            float bc = bconv[n], sc = bnS[n], sh = bnB[n];
            float ps = 0.f;
            #pragma unroll
            for (int mf = 0; mf < MFW; ++mf)
                #pragma unroll
                for (int r = 0; r < 4; r++) {
                    float y = acc[mf][nf][r] + bc;
                    y = fmaxf(y, 0.f);
                    ps += y * sc + sh;
                }
            ps += __shfl_xor(ps, 16, 64);
            ps += __shfl_xor(ps, 32, 64);
            if (lane < 16) atomicAdd(&pooled[gb * COUT + n], ps);
        }
    }
}

template<int CIN, int COUT, bool POOL>
__global__ __launch_bounds__(256, 3) void conv_k(
    const __hip_bfloat16* __restrict__ ain,
    const __hip_bfloat16* __restrict__ Wt,
    const float* __restrict__ bconv,
    const float* __restrict__ bnS,
    const float* __restrict__ bnB,
    __hip_bfloat16* __restrict__ aout,
    float* __restrict__ pooled, int b0, int nimg)
{
    __shared__ __align__(16) __hip_bfloat16 tile[180 * CIN];
    const int tid = threadIdx.x;
    const int lane = tid & 63;
    const int wv = tid >> 6;           // 0..3
    const int mhalf = wv >> 1, nhalf = wv & 1;

    // XCD-aware block swizzle: keep one image's 7 row-groups on one XCD.
    int rg, lb;
    {
        int flat = blockIdx.x + 7 * blockIdx.y;
        if ((nimg & 7) == 0) {
            int xcd = flat & 7, idx = flat >> 3;
            lb = xcd * (nimg >> 3) + idx / 7;
            rg = idx % 7;
        } else {
            rg = blockIdx.x; lb = blockIdx.y;
        }
    }

    // stage 6 padded rows (rg*4 .. rg*4+5) x 30 x CIN, XOR-swizzled (reg-staged)
    const char* src = reinterpret_cast<const char*>(
        ain + ((size_t)lb * 900 + (size_t)rg * 120) * CIN);
    constexpr int TB = 180 * CIN * 2;
    for (int ofs = tid * 16; ofs < TB; ofs += 4096) {
        uint4 v = *reinterpret_cast<const uint4*>(src + ofs);
        *reinterpret_cast<uint4*>(reinterpret_cast<char*>(tile) + (ofs ^ swz<CIN>(ofs))) = v;
    }
    __syncthreads();

    if (mhalf == 0)
        conv_body<CIN, COUT, POOL, 4>(tile, Wt, bconv, bnS, bnB, aout, pooled,
                                      lb, b0 + lb, rg, lane, mhalf, nhalf);
    else
        conv_body<CIN, COUT, POOL, 3>(tile, Wt, bconv, bnS, bnB, aout, pooled,
                                      lb, b0 + lb, rg, lane, mhalf, nhalf);
}

// ---------------- head: mean-pool scale + FC + log-softmax ----------------
__global__ __launch_bounds__(256) void head_k(
    const float* __restrict__ pooled, const float* __restrict__ wfc,
    const float* __restrict__ bfc, float* __restrict__ out)
{
    int b = blockIdx.x * 4 + (threadIdx.x >> 6);
    int lane = threadIdx.x & 63;
    float m0 = pooled[b * 128 + lane] * (1.f / 784.f);
    float m1 = pooled[b * 128 + 64 + lane] * (1.f / 784.f);
    float lg[10];
    #pragma unroll
    for (int k = 0; k < 10; k++) {
        float p = m0 * wfc[k * 128 + lane] + m1 * wfc[k * 128 + 64 + lane];
        #pragma unroll
        for (int s2 = 32; s2 >= 1; s2 >>= 1) p += __shfl_xor(p, s2, 64);
        lg[k] = p + bfc[k];
    }
    float mx = lg[0];
    #pragma unroll
    for (int k = 1; k < 10; k++) mx = fmaxf(mx, lg[k]);
    float se = 0.f;
    #pragma unroll
    for (int k = 0; k < 10; k++) se += expf(lg[k] - mx);
    float lse = mx + logf(se);
    #pragma unroll
    for (int k = 0; k < 10; k++)
        if (lane == k) out[b * 10 + k] = lg[k] - lse;
}

// ---------------- launch ----------------
extern "C" void kernel_launch(void* const* d_in, const int* in_sizes, int n_in,
                              void* d_out, int out_size, void* d_ws, size_t ws_size,
                              hipStream_t stream) {
    (void)in_sizes; (void)n_in; (void)out_size;
    const float* x     = (const float*)d_in[0];
    const float* w_off = (const float*)d_in[1];
    const float* b_off = (const float*)d_in[2];
    const float* w_dcn = (const float*)d_in[3];
    const float* b_dcn = (const float*)d_in[4];
    const float* w2    = (const float*)d_in[5];
    const float* b2    = (const float*)d_in[6];
    const float* w3    = (const float*)d_in[7];
    const float* b3    = (const float*)d_in[8];
    const float* w4    = (const float*)d_in[9];
    const float* b4    = (const float*)d_in[10];
    const float* w_fc  = (const float*)d_in[11];
    const float* b_fc  = (const float*)d_in[12];

    int CH = 256;
    while (CH > 1 && (size_t)CH * ACT_PER_IMG + SZ_FIXED > ws_size) CH >>= 1;
    const int NCHUNK = 1024 / CH;

    char* ws = (char*)d_ws;
    const size_t szA1 = (size_t)CH * 57600;
    const size_t szA2 = (size_t)CH * 115200;
    const size_t szA3 = (size_t)CH * 230400;
    __hip_bfloat16* act1 = (__hip_bfloat16*)(ws);
    __hip_bfloat16* act2 = (__hip_bfloat16*)(ws + szA1);
    __hip_bfloat16* act3 = (__hip_bfloat16*)(ws + szA1 + szA2);
    float* pooled        = (float*)(ws + szA1 + szA2 + szA3);
    __hip_bfloat16* W2   = (__hip_bfloat16*)(ws + szA1 + szA2 + szA3 + SZ_POOL);
    __hip_bfloat16* W3   = (__hip_bfloat16*)((char*)W2 + SZ_W2);
    __hip_bfloat16* W4   = (__hip_bfloat16*)((char*)W3 + SZ_W3);
    float* bn            = (float*)((char*)W4 + SZ_W4);

    PrepArgs pa;
    pa.w2 = w2; pa.w3 = w3; pa.w4 = w4;
    pa.g1 = (const float*)d_in[13]; pa.b1 = (const float*)d_in[14];
    pa.m1 = (const float*)d_in[15]; pa.v1 = (const float*)d_in[16];
    pa.g2 = (const float*)d_in[17]; pa.b2 = (const float*)d_in[18];
    pa.m2 = (const float*)d_in[19]; pa.v2 = (const float*)d_in[20];
    pa.g3 = (const float*)d_in[21]; pa.b3 = (const float*)d_in[22];
    pa.m3 = (const float*)d_in[23]; pa.v3 = (const float*)d_in[24];
    pa.g4 = (const float*)d_in[25]; pa.b4 = (const float*)d_in[26];
    pa.m4 = (const float*)d_in[27]; pa.v4 = (const float*)d_in[28];
    pa.W2 = W2; pa.W3 = W3; pa.W4 = W4; pa.bn = bn;

    prep_k<<<938, 256, 0, stream>>>(pa);
    for (int c = 0; c < NCHUNK; ++c) {
        int b0 = c * CH;
        deform_k<<<CH, 256, 0, stream>>>(x, w_off, b_off, w_dcn, b_dcn, bn,
                                         act1, act2, act3, pooled, b0);
        conv_k<32, 64, false><<<dim3(7, CH), 256, 0, stream>>>(
            act1, W2, b2, bn + 64, bn + 128, act2, nullptr, b0, CH);
        conv_k<64, 128, false><<<dim3(7, CH), 256, 0, stream>>>(
            act2, W3, b3, bn + 192, bn + 320, act3, nullptr, b0, CH);
        conv_k<128, 128, true><<<dim3(7, CH), 256, 0, stream>>>(
            act3, W4, b4, bn + 448, bn + 576, nullptr, pooled, b0, CH);
    }
    head_k<<<256, 256, 0, stream>>>(pooled, w_fc, b_fc, (float*)d_out);
}

// Round 11
// 656.165 us; speedup vs baseline: 1.0511x; 1.0511x over previous
//
#include <hip/hip_runtime.h>
#include <hip/hip_bf16.h>

typedef __bf16 bf16x8 __attribute__((ext_vector_type(8)));
typedef float  f32x4  __attribute__((ext_vector_type(4)));

#define BN_EPS 1e-5f

// Per-image activation bytes (NHWC, padded 30x30):
constexpr size_t ACT_PER_IMG = 57600 + 115200 + 230400;      // 403200
constexpr size_t SZ_POOL = (size_t)1024 * 128 * 4;
constexpr size_t SZ_W2   = (size_t)9 * 64 * 32 * 2;
constexpr size_t SZ_W3   = (size_t)9 * 128 * 64 * 2;
constexpr size_t SZ_W4   = (size_t)9 * 128 * 128 * 2;
constexpr size_t SZ_BN   = 704 * 4;
constexpr size_t SZ_FIXED = SZ_POOL + SZ_W2 + SZ_W3 + SZ_W4 + SZ_BN;

__device__ __forceinline__ unsigned pack2(float a, float b) {
    __hip_bfloat162 h = __float22bfloat162_rn(make_float2(a, b));
    union { __hip_bfloat162 h2; unsigned u; } u;
    u.h2 = h;
    return u.u;
}

// ---------------- prep: weight transform to MFMA-fragment order + BN fold ----
// Fragment order: W'[s][nb][lane][e] -> a wave's B-frag load is 1KB contiguous
// (fixed the r6-r8 VMEM-scatter bottleneck).
struct PrepArgs {
    const float *w2, *w3, *w4;
    const float *g1, *b1, *m1, *v1;
    const float *g2, *b2, *m2, *v2;
    const float *g3, *b3, *m3, *v3;
    const float *g4, *b4, *m4, *v4;
    __hip_bfloat16 *W2, *W3, *W4;
    float *bn;
};

__global__ __launch_bounds__(256) void prep_k(PrepArgs a) {
    int idx = blockIdx.x * 256 + threadIdx.x;
    if (idx < 18432) {            // W2: CIN=32 (KC=1), COUT=64 (NB=4)
        int e = idx & 7, lane = (idx >> 3) & 63, r = idx >> 9;
        int nb = r & 3, t = r >> 2;
        int o = nb * 16 + (lane & 15);
        int i = (lane >> 4) * 8 + e;
        a.W2[idx] = __float2bfloat16(a.w2[(o * 32 + i) * 9 + t]);
        return;
    }
    idx -= 18432;
    if (idx < 73728) {            // W3: CIN=64 (KC=2), COUT=128 (NB=8)
        int e = idx & 7, lane = (idx >> 3) & 63, r = idx >> 9;
        int nb = r & 7, s = r >> 3;
        int kc = s & 1, t = s >> 1;
        int o = nb * 16 + (lane & 15);
        int i = kc * 32 + (lane >> 4) * 8 + e;
        a.W3[idx] = __float2bfloat16(a.w3[(o * 64 + i) * 9 + t]);
        return;
    }
    idx -= 73728;
    if (idx < 147456) {           // W4: CIN=128 (KC=4), COUT=128 (NB=8)
        int e = idx & 7, lane = (idx >> 3) & 63, r = idx >> 9;
        int nb = r & 7, s = r >> 3;
        int kc = s & 3, t = s >> 2;
        int o = nb * 16 + (lane & 15);
        int i = kc * 32 + (lane >> 4) * 8 + e;
        a.W4[idx] = __float2bfloat16(a.w4[(o * 128 + i) * 9 + t]);
        return;
    }
    idx -= 147456;
    if (idx < 352) {
        const float *g, *bb, *mm, *vv; int c, so, cn;
        if (idx < 32)       { g = a.g1; bb = a.b1; mm = a.m1; vv = a.v1; c = idx;       so = 0;   cn = 32;  }
        else if (idx < 96)  { g = a.g2; bb = a.b2; mm = a.m2; vv = a.v2; c = idx - 32;  so = 64;  cn = 64;  }
        else if (idx < 224) { g = a.g3; bb = a.b3; mm = a.m3; vv = a.v3; c = idx - 96;  so = 192; cn = 128; }
        else                { g = a.g4; bb = a.b4; mm = a.m4; vv = a.v4; c = idx - 224; so = 448; cn = 128; }
        float s = g[c] * rsqrtf(vv[c] + BN_EPS);
        a.bn[so + c] = s;
        a.bn[so + cn + c] = bb[c] - mm[c] * s;
    }
}

// ---------------- kernel 1: offsets + deform sample + DCN + BN1 ----------------
__global__ __launch_bounds__(256) void deform_k(
    const float* __restrict__ x, const float* __restrict__ w_off,
    const float* __restrict__ b_off, const float* __restrict__ w_dcn,
    const float* __restrict__ b_dcn, const float* __restrict__ bn,
    __hip_bfloat16* __restrict__ act1, __hip_bfloat16* __restrict__ act2,
    __hip_bfloat16* __restrict__ act3, float* __restrict__ pooled, int b0)
{
    const int lb = blockIdx.x;
    const int b  = b0 + lb;
    const int tid = threadIdx.x;
    __shared__ float xp[900];
    __shared__ float sw[564];
    float* swo = sw;
    float* sbo = sw + 162;
    float* swd = sw + 180;
    float* sbd = sw + 468;
    float* ss1 = sw + 500;
    float* ssh = sw + 532;

    for (int i = tid; i < 900; i += 256) {
        int y = i / 30, xc = i % 30;
        float v = 0.f;
        if (y >= 1 && y <= 28 && xc >= 1 && xc <= 28)
            v = x[(size_t)b * 784 + (y - 1) * 28 + (xc - 1)];
        xp[i] = v;
    }
    for (int i = tid; i < 564; i += 256) {
        float v;
        if (i < 162)      v = w_off[i];
        else if (i < 180) v = b_off[i - 162];
        else if (i < 468) v = w_dcn[i - 180];
        else if (i < 500) v = b_dcn[i - 468];
        else if (i < 532) v = bn[i - 500];
        else              v = bn[32 + (i - 532)];
        sw[i] = v;
    }
    if (tid < 128) pooled[b * 128 + tid] = 0.f;
    __syncthreads();

    for (int p = tid; p < 784; p += 256) {
        int y = p / 28, xx = p % 28;
        float off[18];
        #pragma unroll
        for (int o = 0; o < 18; o++) off[o] = sbo[o];
        #pragma unroll
        for (int ty = 0; ty < 3; ty++)
            #pragma unroll
            for (int tx = 0; tx < 3; tx++) {
                float xv = xp[(y + ty) * 30 + (xx + tx)];
                int tap = ty * 3 + tx;
                #pragma unroll
                for (int o = 0; o < 18; o++) off[o] = fmaf(xv, swo[o * 9 + tap], off[o]);
            }
        float s[9];
        #pragma unroll
        for (int j = 0; j < 9; j++) {
            float py = (float)y + (float)(j / 3 - 1) + off[2 * j];
            float px = (float)xx + (float)(j % 3 - 1) + off[2 * j + 1];
            float y0 = floorf(py), x0 = floorf(px);
            float wy1 = py - y0, wx1 = px - x0;
            float wy0 = 1.f - wy1, wx0 = 1.f - wx1;
            float acc = 0.f;
            #pragma unroll
            for (int cy = 0; cy < 2; cy++)
                #pragma unroll
                for (int cx = 0; cx < 2; cx++) {
                    float yy = y0 + (float)cy, xf = x0 + (float)cx;
                    bool valid = (yy >= 0.f) && (yy <= 27.f) && (xf >= 0.f) && (xf <= 27.f);
                    int yc = (int)fminf(fmaxf(yy, 0.f), 27.f);
                    int xc = (int)fminf(fmaxf(xf, 0.f), 27.f);
                    float g = valid ? xp[(yc + 1) * 30 + (xc + 1)] : 0.f;
                    float w = (cy ? wy1 : wy0) * (cx ? wx1 : wx0);
                    acc = fmaf(g, w, acc);
                }
            s[j] = acc;
        }
        size_t base = ((size_t)lb * 900 + (size_t)(y + 1) * 30 + (xx + 1)) * 32;
        #pragma unroll
        for (int c0 = 0; c0 < 32; c0 += 8) {
            float h[8];
            #pragma unroll
            for (int ci = 0; ci < 8; ci++) {
                int c = c0 + ci;
                float hv = sbd[c];
                #pragma unroll
                for (int j = 0; j < 9; j++) hv = fmaf(s[j], swd[c * 9 + j], hv);
                h[ci] = hv * ss1[c] + ssh[c];
            }
            uint4 q;
            q.x = pack2(h[0], h[1]); q.y = pack2(h[2], h[3]);
            q.z = pack2(h[4], h[5]); q.w = pack2(h[6], h[7]);
            *reinterpret_cast<uint4*>(&act1[base + c0]) = q;
        }
    }

    for (int i = tid; i < 116; i += 256) {
        int py, px;
        if (i < 30)      { py = 0;          px = i; }
        else if (i < 60) { py = 29;         px = i - 30; }
        else if (i < 88) { py = i - 60 + 1; px = 0; }
        else             { py = i - 88 + 1; px = 29; }
        size_t pix = (size_t)lb * 900 + (size_t)py * 30 + px;
        uint4 z = {0, 0, 0, 0};
        uint4* p1 = reinterpret_cast<uint4*>(&act1[pix * 32]);
        #pragma unroll
        for (int k = 0; k < 4; k++) p1[k] = z;
        uint4* p2 = reinterpret_cast<uint4*>(&act2[pix * 64]);
        #pragma unroll
        for (int k = 0; k < 8; k++) p2[k] = z;
        uint4* p3 = reinterpret_cast<uint4*>(&act3[pix * 128]);
        #pragma unroll
        for (int k = 0; k < 16; k++) p3[k] = z;
    }
}

// ---------------- conv 3x3 (implicit GEMM, MFMA bf16, 3-deep pipeline) --------
template<int CIN>
__device__ __forceinline__ int swz(int ofs) {
    if constexpr (CIN == 128) return (ofs >> 4) & 0x70;      // bits 8-10 -> 4-6
    else if constexpr (CIN == 64) return (ofs >> 3) & 0x70;  // bits 7-9  -> 4-6
    else return (ofs >> 2) & 0x30;                           // bits 6-7  -> 4-5
}

// Weight fragment load, fragment-order layout: contiguous 1KB per frag per wave.
template<int COUT, int NFW>
__device__ __forceinline__ void loadWf(const __hip_bfloat16* __restrict__ Wt,
                                       int s, int nhalf, int lane, bf16x8 (&bf)[NFW]) {
    constexpr int NB = COUT / 16;
    #pragma unroll
    for (int nf = 0; nf < NFW; ++nf)
        bf[nf] = *reinterpret_cast<const bf16x8*>(
            Wt + (((size_t)s * NB + nhalf * NFW + nf) * 64 + lane) * 8);
}

template<int CIN, int MFW>
__device__ __forceinline__ void loadAf(const __hip_bfloat16* tile,
                                       int s, const int (&pr)[4], const int (&pc)[4],
                                       int kg, bf16x8 (&af)[MFW]) {
    constexpr int KC = CIN / 32;
    int t = s / KC, kc = (s % KC) * 32;
    int ty = t / 3, tx = t % 3;
    #pragma unroll
    for (int mf = 0; mf < MFW; ++mf) {
        int pix = (pr[mf] + ty) * 30 + (pc[mf] + tx);
        int ba = (pix * CIN + kc + kg * 8) * 2;
        ba ^= swz<CIN>(ba);
        af[mf] = *reinterpret_cast<const bf16x8*>(
            reinterpret_cast<const char*>(tile) + ba);
    }
}

template<int MFW, int NFW>
__device__ __forceinline__ void mstep(const bf16x8 (&af)[MFW], const bf16x8 (&wf)[NFW],
                                      f32x4 (&acc)[MFW][NFW]) {
    #pragma unroll
    for (int mf = 0; mf < MFW; ++mf)
        #pragma unroll
        for (int nf = 0; nf < NFW; ++nf)
            acc[mf][nf] = __builtin_amdgcn_mfma_f32_16x16x32_bf16(
                af[mf], wf[nf], acc[mf][nf], 0, 0, 0);
}

// 4 waves per block, NFW=COUT/32. Per-step operand latency (L2 weight ~200cyc,
// ds_read ~120cyc) exceeded the 1-step prefetch (~78cyc of MFMA issue) -> 38%
// MfmaUtil plateau (r9/r10). Fix: 3-deep statically-rotated pipeline (prefetch
// distance 2) with sched_barrier(0) pinning loads above each MFMA cluster so
// hipcc cannot collapse the distance (it did in r5/r6: VGPR 76/72).
template<int CIN, int COUT, bool POOL, int MFW>
__device__ __forceinline__ void conv_body(
    const __hip_bfloat16* tile,
    const __hip_bfloat16* __restrict__ Wt,
    const float* __restrict__ bconv, const float* __restrict__ bnS,
    const float* __restrict__ bnB, __hip_bfloat16* __restrict__ aout,
    float* __restrict__ pooled, int lb, int gb, int rg, int lane, int mhalf, int nhalf)
{
    constexpr int KC  = CIN / 32;
    constexpr int NS  = 9 * KC;          // 9 / 18 / 36 — all multiples of 3
    constexpr int NFW = COUT / 32;
    const int l15 = lane & 15, kg = lane >> 4;
    const int nbase = nhalf * (NFW * 16) + l15;

    int pr[4], pc[4];
    #pragma unroll
    for (int mf = 0; mf < MFW; ++mf) {
        int m = (mhalf * 4 + mf) * 16 + l15;
        pr[mf] = m / 28;
        pc[mf] = m % 28;
    }

    f32x4 acc[MFW][NFW] = {};
    bf16x8 wA[NFW], wB[NFW], wC[NFW];
    bf16x8 aA[MFW], aB[MFW], aC[MFW];

    // prologue: fill pipeline 2 steps deep
    loadWf<COUT, NFW>(Wt, 0, nhalf, lane, wA);
    loadAf<CIN, MFW>(tile, 0, pr, pc, kg, aA);
    loadWf<COUT, NFW>(Wt, 1, nhalf, lane, wB);
    loadAf<CIN, MFW>(tile, 1, pr, pc, kg, aB);

    #pragma unroll
    for (int s = 0; s < NS; s += 3) {
        if (s + 2 < NS) {
            loadWf<COUT, NFW>(Wt, s + 2, nhalf, lane, wC);
            loadAf<CIN, MFW>(tile, s + 2, pr, pc, kg, aC);
        }
        __builtin_amdgcn_sched_barrier(0);
        mstep<MFW, NFW>(aA, wA, acc);
        if (s + 3 < NS) {
            loadWf<COUT, NFW>(Wt, s + 3, nhalf, lane, wA);
            loadAf<CIN, MFW>(tile, s + 3, pr, pc, kg, aA);
        }
        __builtin_amdgcn_sched_barrier(0);
        mstep<MFW, NFW>(aB, wB, acc);
        if (s + 4 < NS) {
            loadWf<COUT, NFW>(Wt, s + 4, nhalf, lane, wB);
            loadAf<CIN, MFW>(tile, s + 4, pr, pc, kg, aB);
        }
        __builtin_amdgcn_sched_barrier(0);
        if (s + 2 < NS) mstep<MFW, NFW>(aC, wC, acc);
    }

    if constexpr (!POOL) {
        #pragma unroll
        for (int mf = 0; mf < MFW; ++mf) {
            #pragma unroll
            for (int nf = 0; nf < NFW; ++nf) {
                int n = nbase + nf * 16;
                float bc = bconv[n], sc = bnS[n], sh = bnB[n];
                #pragma unroll
                for (int r = 0; r < 4; r++) {
                    int m = (mhalf * 4 + mf) * 16 + kg * 4 + r;
                    float y = acc[mf][nf][r] + bc;
                    y = fmaxf(y, 0.f);
                    y = y * sc + sh;
                    int oy = m / 28, ox = m % 28;
                    aout[((size_t)lb * 900 + (size_t)(rg * 4 + oy + 1) * 30 + (ox + 1)) * COUT + n]
                        = __float2bfloat16(y);
                }
            }
        }
    } else {
        #pragma unroll
        for (int nf = 0; nf < NFW; ++nf) {
            int n = nbase + nf * 16;
            float bc = bconv[n], sc = bnS[n], sh = bnB[n];
            float ps = 0.f;
            #pragma unroll
            for (int mf = 0; mf < MFW; ++mf)
                #pragma unroll
                for (int r = 0; r < 4; r++) {
                    float y = acc[mf][nf][r] + bc;
                    y = fmaxf(y, 0.f);
                    ps += y * sc + sh;
                }
            ps += __shfl_xor(ps, 16, 64);
            ps += __shfl_xor(ps, 32, 64);
            if (lane < 16) atomicAdd(&pooled[gb * COUT + n], ps);
        }
    }
}

template<int CIN, int COUT, bool POOL>
__global__ __launch_bounds__(256, 2) void conv_k(
    const __hip_bfloat16* __restrict__ ain,
    const __hip_bfloat16* __restrict__ Wt,
    const float* __restrict__ bconv,
    const float* __restrict__ bnS,
    const float* __restrict__ bnB,
    __hip_bfloat16* __restrict__ aout,
    float* __restrict__ pooled, int b0, int nimg)
{
    __shared__ __align__(16) __hip_bfloat16 tile[180 * CIN];
    const int tid = threadIdx.x;
    const int lane = tid & 63;
    const int wv = tid >> 6;           // 0..3
    const int mhalf = wv >> 1, nhalf = wv & 1;

    // XCD-aware block swizzle: keep one image's 7 row-groups on one XCD.
    int rg, lb;
    {
        int flat = blockIdx.x + 7 * blockIdx.y;
        if ((nimg & 7) == 0) {
            int xcd = flat & 7, idx = flat >> 3;
            lb = xcd * (nimg >> 3) + idx / 7;
            rg = idx % 7;
        } else {
            rg = blockIdx.x; lb = blockIdx.y;
        }
    }

    // stage 6 padded rows (rg*4 .. rg*4+5) x 30 x CIN, XOR-swizzled (reg-staged)
    const char* src = reinterpret_cast<const char*>(
        ain + ((size_t)lb * 900 + (size_t)rg * 120) * CIN);
    constexpr int TB = 180 * CIN * 2;
    for (int ofs = tid * 16; ofs < TB; ofs += 4096) {
        uint4 v = *reinterpret_cast<const uint4*>(src + ofs);
        *reinterpret_cast<uint4*>(reinterpret_cast<char*>(tile) + (ofs ^ swz<CIN>(ofs))) = v;
    }
    __syncthreads();

    if (mhalf == 0)
        conv_body<CIN, COUT, POOL, 4>(tile, Wt, bconv, bnS, bnB, aout, pooled,
                                      lb, b0 + lb, rg, lane, mhalf, nhalf);
    else
        conv_body<CIN, COUT, POOL, 3>(tile, Wt, bconv, bnS, bnB, aout, pooled,
                                      lb, b0 + lb, rg, lane, mhalf, nhalf);
}

// ---------------- head: mean-pool scale + FC + log-softmax ----------------
__global__ __launch_bounds__(256) void head_k(
    const float* __restrict__ pooled, const float* __restrict__ wfc,
    const float* __restrict__ bfc, float* __restrict__ out)
{
    int b = blockIdx.x * 4 + (threadIdx.x >> 6);
    int lane = threadIdx.x & 63;
    float m0 = pooled[b * 128 + lane] * (1.f / 784.f);
    float m1 = pooled[b * 128 + 64 + lane] * (1.f / 784.f);
    float lg[10];
    #pragma unroll
    for (int k = 0; k < 10; k++) {
        float p = m0 * wfc[k * 128 + lane] + m1 * wfc[k * 128 + 64 + lane];
        #pragma unroll
        for (int s2 = 32; s2 >= 1; s2 >>= 1) p += __shfl_xor(p, s2, 64);
        lg[k] = p + bfc[k];
    }
    float mx = lg[0];
    #pragma unroll
    for (int k = 1; k < 10; k++) mx = fmaxf(mx, lg[k]);
    float se = 0.f;
    #pragma unroll
    for (int k = 0; k < 10; k++) se += expf(lg[k] - mx);
    float lse = mx + logf(se);
    #pragma unroll
    for (int k = 0; k < 10; k++)
        if (lane == k) out[b * 10 + k] = lg[k] - lse;
}

// ---------------- launch ----------------
extern "C" void kernel_launch(void* const* d_in, const int* in_sizes, int n_in,
                              void* d_out, int out_size, void* d_ws, size_t ws_size,
                              hipStream_t stream) {
    (void)in_sizes; (void)n_in; (void)out_size;
    const float* x     = (const float*)d_in[0];
    const float* w_off = (const float*)d_in[1];
    const float* b_off = (const float*)d_in[2];
    const float* w_dcn = (const float*)d_in[3];
    const float* b_dcn = (const float*)d_in[4];
    const float* w2    = (const float*)d_in[5];
    const float* b2    = (const float*)d_in[6];
    const float* w3    = (const float*)d_in[7];
    const float* b3    = (const float*)d_in[8];
    const float* w4    = (const float*)d_in[9];
    const float* b4    = (const float*)d_in[10];
    const float* w_fc  = (const float*)d_in[11];
    const float* b_fc  = (const float*)d_in[12];

    int CH = 256;
    while (CH > 1 && (size_t)CH * ACT_PER_IMG + SZ_FIXED > ws_size) CH >>= 1;
    const int NCHUNK = 1024 / CH;

    char* ws = (char*)d_ws;
    const size_t szA1 = (size_t)CH * 57600;
    const size_t szA2 = (size_t)CH * 115200;
    const size_t szA3 = (size_t)CH * 230400;
    __hip_bfloat16* act1 = (__hip_bfloat16*)(ws);
    __hip_bfloat16* act2 = (__hip_bfloat16*)(ws + szA1);
    __hip_bfloat16* act3 = (__hip_bfloat16*)(ws + szA1 + szA2);
    float* pooled        = (float*)(ws + szA1 + szA2 + szA3);
    __hip_bfloat16* W2   = (__hip_bfloat16*)(ws + szA1 + szA2 + szA3 + SZ_POOL);
    __hip_bfloat16* W3   = (__hip_bfloat16*)((char*)W2 + SZ_W2);
    __hip_bfloat16* W4   = (__hip_bfloat16*)((char*)W3 + SZ_W3);
    float* bn            = (float*)((char*)W4 + SZ_W4);

    PrepArgs pa;
    pa.w2 = w2; pa.w3 = w3; pa.w4 = w4;
    pa.g1 = (const float*)d_in[13]; pa.b1 = (const float*)d_in[14];
    pa.m1 = (const float*)d_in[15]; pa.v1 = (const float*)d_in[16];
    pa.g2 = (const float*)d_in[17]; pa.b2 = (const float*)d_in[18];
    pa.m2 = (const float*)d_in[19]; pa.v2 = (const float*)d_in[20];
    pa.g3 = (const float*)d_in[21]; pa.b3 = (const float*)d_in[22];
    pa.m3 = (const float*)d_in[23]; pa.v3 = (const float*)d_in[24];
    pa.g4 = (const float*)d_in[25]; pa.b4 = (const float*)d_in[26];
    pa.m4 = (const float*)d_in[27]; pa.v4 = (const float*)d_in[28];
    pa.W2 = W2; pa.W3 = W3; pa.W4 = W4; pa.bn = bn;

    prep_k<<<938, 256, 0, stream>>>(pa);
    for (int c = 0; c < NCHUNK; ++c) {
        int b0 = c * CH;
        deform_k<<<CH, 256, 0, stream>>>(x, w_off, b_off, w_dcn, b_dcn, bn,
                                         act1, act2, act3, pooled, b0);
        conv_k<32, 64, false><<<dim3(7, CH), 256, 0, stream>>>(
            act1, W2, b2, bn + 64, bn + 128, act2, nullptr, b0, CH);
        conv_k<64, 128, false><<<dim3(7, CH), 256, 0, stream>>>(
            act2, W3, b3, bn + 192, bn + 320, act3, nullptr, b0, CH);
        conv_k<128, 128, true><<<dim3(7, CH), 256, 0, stream>>>(
            act3, W4, b4, bn + 448, bn + 576, nullptr, pooled, b0, CH);
    }
    head_k<<<256, 256, 0, stream>>>(pooled, w_fc, b_fc, (float*)d_out);
}

// Round 12
// 648.006 us; speedup vs baseline: 1.0644x; 1.0126x over previous
//
#include <hip/hip_runtime.h>
#include <hip/hip_bf16.h>

typedef __bf16 bf16x8 __attribute__((ext_vector_type(8)));
typedef float  f32x4  __attribute__((ext_vector_type(4)));

#define BN_EPS 1e-5f

// Per-image activation bytes (NHWC, padded 30x30):
constexpr size_t ACT_PER_IMG = 57600 + 115200 + 230400;      // 403200
constexpr size_t SZ_POOL = (size_t)1024 * 128 * 4;
constexpr size_t SZ_W2   = (size_t)9 * 64 * 32 * 2;
constexpr size_t SZ_W3   = (size_t)9 * 128 * 64 * 2;
constexpr size_t SZ_W4   = (size_t)9 * 128 * 128 * 2;
constexpr size_t SZ_BN   = 704 * 4;
constexpr size_t SZ_FIXED = SZ_POOL + SZ_W2 + SZ_W3 + SZ_W4 + SZ_BN;

__device__ __forceinline__ unsigned pack2(float a, float b) {
    __hip_bfloat162 h = __float22bfloat162_rn(make_float2(a, b));
    union { __hip_bfloat162 h2; unsigned u; } u;
    u.h2 = h;
    return u.u;
}

// ---------------- prep: weight transform to MFMA-fragment order + BN fold ----
// Fragment order: W'[s][nb][lane][e] -> a wave's B-frag load is 1KB contiguous.
struct PrepArgs {
    const float *w2, *w3, *w4;
    const float *g1, *b1, *m1, *v1;
    const float *g2, *b2, *m2, *v2;
    const float *g3, *b3, *m3, *v3;
    const float *g4, *b4, *m4, *v4;
    __hip_bfloat16 *W2, *W3, *W4;
    float *bn;
};

__global__ __launch_bounds__(256) void prep_k(PrepArgs a) {
    int idx = blockIdx.x * 256 + threadIdx.x;
    if (idx < 18432) {            // W2: CIN=32 (KC=1), COUT=64 (NB=4)
        int e = idx & 7, lane = (idx >> 3) & 63, r = idx >> 9;
        int nb = r & 3, t = r >> 2;
        int o = nb * 16 + (lane & 15);
        int i = (lane >> 4) * 8 + e;
        a.W2[idx] = __float2bfloat16(a.w2[(o * 32 + i) * 9 + t]);
        return;
    }
    idx -= 18432;
    if (idx < 73728) {            // W3: CIN=64 (KC=2), COUT=128 (NB=8)
        int e = idx & 7, lane = (idx >> 3) & 63, r = idx >> 9;
        int nb = r & 7, s = r >> 3;
        int kc = s & 1, t = s >> 1;
        int o = nb * 16 + (lane & 15);
        int i = kc * 32 + (lane >> 4) * 8 + e;
        a.W3[idx] = __float2bfloat16(a.w3[(o * 64 + i) * 9 + t]);
        return;
    }
    idx -= 73728;
    if (idx < 147456) {           // W4: CIN=128 (KC=4), COUT=128 (NB=8)
        int e = idx & 7, lane = (idx >> 3) & 63, r = idx >> 9;
        int nb = r & 7, s = r >> 3;
        int kc = s & 3, t = s >> 2;
        int o = nb * 16 + (lane & 15);
        int i = kc * 32 + (lane >> 4) * 8 + e;
        a.W4[idx] = __float2bfloat16(a.w4[(o * 128 + i) * 9 + t]);
        return;
    }
    idx -= 147456;
    if (idx < 352) {
        const float *g, *bb, *mm, *vv; int c, so, cn;
        if (idx < 32)       { g = a.g1; bb = a.b1; mm = a.m1; vv = a.v1; c = idx;       so = 0;   cn = 32;  }
        else if (idx < 96)  { g = a.g2; bb = a.b2; mm = a.m2; vv = a.v2; c = idx - 32;  so = 64;  cn = 64;  }
        else if (idx < 224) { g = a.g3; bb = a.b3; mm = a.m3; vv = a.v3; c = idx - 96;  so = 192; cn = 128; }
        else                { g = a.g4; bb = a.b4; mm = a.m4; vv = a.v4; c = idx - 224; so = 448; cn = 128; }
        float s = g[c] * rsqrtf(vv[c] + BN_EPS);
        a.bn[so + c] = s;
        a.bn[so + cn + c] = bb[c] - mm[c] * s;
    }
}

// ---------------- kernel 1: offsets + deform sample + DCN + BN1 ----------------
__global__ __launch_bounds__(256) void deform_k(
    const float* __restrict__ x, const float* __restrict__ w_off,
    const float* __restrict__ b_off, const float* __restrict__ w_dcn,
    const float* __restrict__ b_dcn, const float* __restrict__ bn,
    __hip_bfloat16* __restrict__ act1, __hip_bfloat16* __restrict__ act2,
    __hip_bfloat16* __restrict__ act3, float* __restrict__ pooled, int b0)
{
    const int lb = blockIdx.x;
    const int b  = b0 + lb;
    const int tid = threadIdx.x;
    __shared__ float xp[900];
    __shared__ float sw[564];
    float* swo = sw;
    float* sbo = sw + 162;
    float* swd = sw + 180;
    float* sbd = sw + 468;
    float* ss1 = sw + 500;
    float* ssh = sw + 532;

    for (int i = tid; i < 900; i += 256) {
        int y = i / 30, xc = i % 30;
        float v = 0.f;
        if (y >= 1 && y <= 28 && xc >= 1 && xc <= 28)
            v = x[(size_t)b * 784 + (y - 1) * 28 + (xc - 1)];
        xp[i] = v;
    }
    for (int i = tid; i < 564; i += 256) {
        float v;
        if (i < 162)      v = w_off[i];
        else if (i < 180) v = b_off[i - 162];
        else if (i < 468) v = w_dcn[i - 180];
        else if (i < 500) v = b_dcn[i - 468];
        else if (i < 532) v = bn[i - 500];
        else              v = bn[32 + (i - 532)];
        sw[i] = v;
    }
    if (tid < 128) pooled[b * 128 + tid] = 0.f;
    __syncthreads();

    for (int p = tid; p < 784; p += 256) {
        int y = p / 28, xx = p % 28;
        float off[18];
        #pragma unroll
        for (int o = 0; o < 18; o++) off[o] = sbo[o];
        #pragma unroll
        for (int ty = 0; ty < 3; ty++)
            #pragma unroll
            for (int tx = 0; tx < 3; tx++) {
                float xv = xp[(y + ty) * 30 + (xx + tx)];
                int tap = ty * 3 + tx;
                #pragma unroll
                for (int o = 0; o < 18; o++) off[o] = fmaf(xv, swo[o * 9 + tap], off[o]);
            }
        float s[9];
        #pragma unroll
        for (int j = 0; j < 9; j++) {
            float py = (float)y + (float)(j / 3 - 1) + off[2 * j];
            float px = (float)xx + (float)(j % 3 - 1) + off[2 * j + 1];
            float y0 = floorf(py), x0 = floorf(px);
            float wy1 = py - y0, wx1 = px - x0;
            float wy0 = 1.f - wy1, wx0 = 1.f - wx1;
            float acc = 0.f;
            #pragma unroll
            for (int cy = 0; cy < 2; cy++)
                #pragma unroll
                for (int cx = 0; cx < 2; cx++) {
                    float yy = y0 + (float)cy, xf = x0 + (float)cx;
                    bool valid = (yy >= 0.f) && (yy <= 27.f) && (xf >= 0.f) && (xf <= 27.f);
                    int yc = (int)fminf(fmaxf(yy, 0.f), 27.f);
                    int xc = (int)fminf(fmaxf(xf, 0.f), 27.f);
                    float g = valid ? xp[(yc + 1) * 30 + (xc + 1)] : 0.f;
                    float w = (cy ? wy1 : wy0) * (cx ? wx1 : wx0);
                    acc = fmaf(g, w, acc);
                }
            s[j] = acc;
        }
        size_t base = ((size_t)lb * 900 + (size_t)(y + 1) * 30 + (xx + 1)) * 32;
        #pragma unroll
        for (int c0 = 0; c0 < 32; c0 += 8) {
            float h[8];
            #pragma unroll
            for (int ci = 0; ci < 8; ci++) {
                int c = c0 + ci;
                float hv = sbd[c];
                #pragma unroll
                for (int j = 0; j < 9; j++) hv = fmaf(s[j], swd[c * 9 + j], hv);
                h[ci] = hv * ss1[c] + ssh[c];
            }
            uint4 q;
            q.x = pack2(h[0], h[1]); q.y = pack2(h[2], h[3]);
            q.z = pack2(h[4], h[5]); q.w = pack2(h[6], h[7]);
            *reinterpret_cast<uint4*>(&act1[base + c0]) = q;
        }
    }

    for (int i = tid; i < 116; i += 256) {
        int py, px;
        if (i < 30)      { py = 0;          px = i; }
        else if (i < 60) { py = 29;         px = i - 30; }
        else if (i < 88) { py = i - 60 + 1; px = 0; }
        else             { py = i - 88 + 1; px = 29; }
        size_t pix = (size_t)lb * 900 + (size_t)py * 30 + px;
        uint4 z = {0, 0, 0, 0};
        uint4* p1 = reinterpret_cast<uint4*>(&act1[pix * 32]);
        #pragma unroll
        for (int k = 0; k < 4; k++) p1[k] = z;
        uint4* p2 = reinterpret_cast<uint4*>(&act2[pix * 64]);
        #pragma unroll
        for (int k = 0; k < 8; k++) p2[k] = z;
        uint4* p3 = reinterpret_cast<uint4*>(&act3[pix * 128]);
        #pragma unroll
        for (int k = 0; k < 16; k++) p3[k] = z;
    }
}

// ---------------- conv 3x3: 2-wave blocks, waves partition N only ------------
// Per K-step per block: A-reads 2x7 (was 4x3.5), W-loads 2xNFW (halved vs r9-r11
// because no m-split wave duplicates the weight stream). Per-CU pipe budget
// (conv4): MFMA 68K cyc (max), LDS ~61K, weight-VMEM 32K -> MFMA-capped.
template<int CIN>
__device__ __forceinline__ int swz(int ofs) {
    if constexpr (CIN == 128) return (ofs >> 4) & 0x70;      // bits 8-10 -> 4-6
    else if constexpr (CIN == 64) return (ofs >> 3) & 0x70;  // bits 7-9  -> 4-6
    else return (ofs >> 2) & 0x30;                           // bits 6-7  -> 4-5
}

template<int COUT, int NFW>
__device__ __forceinline__ void loadWf(const __hip_bfloat16* __restrict__ Wt,
                                       int s, int nq, int lane, bf16x8 (&bf)[NFW]) {
    constexpr int NB = COUT / 16;
    #pragma unroll
    for (int nf = 0; nf < NFW; ++nf)
        bf[nf] = *reinterpret_cast<const bf16x8*>(
            Wt + (((size_t)s * NB + nq * NFW + nf) * 64 + lane) * 8);
}

template<int CIN>
__device__ __forceinline__ void loadAf(const __hip_bfloat16* tile,
                                       int s, const int (&pr)[7], const int (&pc)[7],
                                       int kg, bf16x8 (&af)[7]) {
    constexpr int KC = CIN / 32;
    int t = s / KC, kc = (s % KC) * 32;
    int ty = t / 3, tx = t % 3;
    #pragma unroll
    for (int mf = 0; mf < 7; ++mf) {
        int pix = (pr[mf] + ty) * 30 + (pc[mf] + tx);
        int ba = (pix * CIN + kc + kg * 8) * 2;
        ba ^= swz<CIN>(ba);
        af[mf] = *reinterpret_cast<const bf16x8*>(
            reinterpret_cast<const char*>(tile) + ba);
    }
}

template<int NFW>
__device__ __forceinline__ void mstep7(const bf16x8 (&af)[7], const bf16x8 (&wf)[NFW],
                                       f32x4 (&acc)[7][NFW]) {
    #pragma unroll
    for (int mf = 0; mf < 7; ++mf)
        #pragma unroll
        for (int nf = 0; nf < NFW; ++nf)
            acc[mf][nf] = __builtin_amdgcn_mfma_f32_16x16x32_bf16(
                af[mf], wf[nf], acc[mf][nf], 0, 0, 0);
}

template<int CIN, int COUT, bool POOL>
__device__ __forceinline__ void conv_body(
    const __hip_bfloat16* tile,
    const __hip_bfloat16* __restrict__ Wt,
    const float* __restrict__ bconv, const float* __restrict__ bnS,
    const float* __restrict__ bnB, __hip_bfloat16* __restrict__ aout,
    float* __restrict__ pooled, int lb, int gb, int rg, int lane, int nq)
{
    constexpr int KC  = CIN / 32;
    constexpr int NS  = 9 * KC;          // 9 / 18 / 36
    constexpr int NFW = COUT / 32;       // 2 / 4 / 4
    const int l15 = lane & 15, kg = lane >> 4;
    const int nbase = nq * (NFW * 16) + l15;

    int pr[7], pc[7];
    #pragma unroll
    for (int mf = 0; mf < 7; ++mf) {
        int m = mf * 16 + l15;
        pr[mf] = m / 28;
        pc[mf] = m % 28;
    }

    f32x4 acc[7][NFW] = {};
    bf16x8 wA[NFW], wB[NFW], aA[7], aB[7];

    loadWf<COUT, NFW>(Wt, 0, nq, lane, wA);
    loadAf<CIN>(tile, 0, pr, pc, kg, aA);
    loadWf<COUT, NFW>(Wt, 1, nq, lane, wB);
    loadAf<CIN>(tile, 1, pr, pc, kg, aB);

    #pragma unroll
    for (int s = 0; s < NS; s += 2) {
        __builtin_amdgcn_sched_barrier(0);
        mstep7<NFW>(aA, wA, acc);
        if (s + 2 < NS) {
            loadWf<COUT, NFW>(Wt, s + 2, nq, lane, wA);
            loadAf<CIN>(tile, s + 2, pr, pc, kg, aA);
        }
        __builtin_amdgcn_sched_barrier(0);
        if (s + 1 < NS) {
            mstep7<NFW>(aB, wB, acc);
            if (s + 3 < NS) {
                loadWf<COUT, NFW>(Wt, s + 3, nq, lane, wB);
                loadAf<CIN>(tile, s + 3, pr, pc, kg, aB);
            }
        }
    }

    if constexpr (!POOL) {
        #pragma unroll
        for (int mf = 0; mf < 7; ++mf) {
            #pragma unroll
            for (int nf = 0; nf < NFW; ++nf) {
                int n = nbase + nf * 16;
                float bc = bconv[n], sc = bnS[n], sh = bnB[n];
                #pragma unroll
                for (int r = 0; r < 4; r++) {
                    int m = mf * 16 + kg * 4 + r;
                    float y = acc[mf][nf][r] + bc;
                    y = fmaxf(y, 0.f);
                    y = y * sc + sh;
                    int oy = m / 28, ox = m % 28;
                    aout[((size_t)lb * 900 + (size_t)(rg * 4 + oy + 1) * 30 + (ox + 1)) * COUT + n]
                        = __float2bfloat16(y);
                }
            }
        }
    } else {
        #pragma unroll
        for (int nf = 0; nf < NFW; ++nf) {
            int n = nbase + nf * 16;
            float bc = bconv[n], sc = bnS[n], sh = bnB[n];
            float ps = 0.f;
            #pragma unroll
            for (int mf = 0; mf < 7; ++mf)
                #pragma unroll
                for (int r = 0; r < 4; r++) {
                    float y = acc[mf][nf][r] + bc;
                    y = fmaxf(y, 0.f);
                    ps += y * sc + sh;
                }
            ps += __shfl_xor(ps, 16, 64);
            ps += __shfl_xor(ps, 32, 64);
            if (lane < 16) atomicAdd(&pooled[gb * COUT + n], ps);
        }
    }
}

template<int CIN, int COUT, bool POOL>
__global__ __launch_bounds__(128, 2) void conv_k(
    const __hip_bfloat16* __restrict__ ain,
    const __hip_bfloat16* __restrict__ Wt,
    const float* __restrict__ bconv,
    const float* __restrict__ bnS,
    const float* __restrict__ bnB,
    __hip_bfloat16* __restrict__ aout,
    float* __restrict__ pooled, int b0, int nimg)
{
    __shared__ __align__(16) __hip_bfloat16 tile[180 * CIN];
    const int tid = threadIdx.x;
    const int lane = tid & 63;
    const int nq = tid >> 6;           // 0..1 — waves partition N only

    // XCD-aware block swizzle: keep one image's 7 row-groups on one XCD.
    int rg, lb;
    {
        int flat = blockIdx.x + 7 * blockIdx.y;
        if ((nimg & 7) == 0) {
            int xcd = flat & 7, idx = flat >> 3;
            lb = xcd * (nimg >> 3) + idx / 7;
            rg = idx % 7;
        } else {
            rg = blockIdx.x; lb = blockIdx.y;
        }
    }

    // stage 6 padded rows (rg*4 .. rg*4+5) x 30 x CIN, XOR-swizzled (reg-staged)
    const char* src = reinterpret_cast<const char*>(
        ain + ((size_t)lb * 900 + (size_t)rg * 120) * CIN);
    constexpr int TB = 180 * CIN * 2;
    for (int ofs = tid * 16; ofs < TB; ofs += 2048) {
        uint4 v = *reinterpret_cast<const uint4*>(src + ofs);
        *reinterpret_cast<uint4*>(reinterpret_cast<char*>(tile) + (ofs ^ swz<CIN>(ofs))) = v;
    }
    __syncthreads();

    conv_body<CIN, COUT, POOL>(tile, Wt, bconv, bnS, bnB, aout, pooled,
                               lb, b0 + lb, rg, lane, nq);
}

// ---------------- head: mean-pool scale + FC + log-softmax ----------------
__global__ __launch_bounds__(256) void head_k(
    const float* __restrict__ pooled, const float* __restrict__ wfc,
    const float* __restrict__ bfc, float* __restrict__ out)
{
    int b = blockIdx.x * 4 + (threadIdx.x >> 6);
    int lane = threadIdx.x & 63;
    float m0 = pooled[b * 128 + lane] * (1.f / 784.f);
    float m1 = pooled[b * 128 + 64 + lane] * (1.f / 784.f);
    float lg[10];
    #pragma unroll
    for (int k = 0; k < 10; k++) {
        float p = m0 * wfc[k * 128 + lane] + m1 * wfc[k * 128 + 64 + lane];
        #pragma unroll
        for (int s2 = 32; s2 >= 1; s2 >>= 1) p += __shfl_xor(p, s2, 64);
        lg[k] = p + bfc[k];
    }
    float mx = lg[0];
    #pragma unroll
    for (int k = 1; k < 10; k++) mx = fmaxf(mx, lg[k]);
    float se = 0.f;
    #pragma unroll
    for (int k = 0; k < 10; k++) se += expf(lg[k] - mx);
    float lse = mx + logf(se);
    #pragma unroll
    for (int k = 0; k < 10; k++)
        if (lane == k) out[b * 10 + k] = lg[k] - lse;
}

// ---------------- launch ----------------
extern "C" void kernel_launch(void* const* d_in, const int* in_sizes, int n_in,
                              void* d_out, int out_size, void* d_ws, size_t ws_size,
                              hipStream_t stream) {
    (void)in_sizes; (void)n_in; (void)out_size;
    const float* x     = (const float*)d_in[0];
    const float* w_off = (const float*)d_in[1];
    const float* b_off = (const float*)d_in[2];
    const float* w_dcn = (const float*)d_in[3];
    const float* b_dcn = (const float*)d_in[4];
    const float* w2    = (const float*)d_in[5];
    const float* b2    = (const float*)d_in[6];
    const float* w3    = (const float*)d_in[7];
    const float* b3    = (const float*)d_in[8];
    const float* w4    = (const float*)d_in[9];
    const float* b4    = (const float*)d_in[10];
    const float* w_fc  = (const float*)d_in[11];
    const float* b_fc  = (const float*)d_in[12];

    int CH = 256;
    while (CH > 1 && (size_t)CH * ACT_PER_IMG + SZ_FIXED > ws_size) CH >>= 1;
    const int NCHUNK = 1024 / CH;

    char* ws = (char*)d_ws;
    const size_t szA1 = (size_t)CH * 57600;
    const size_t szA2 = (size_t)CH * 115200;
    const size_t szA3 = (size_t)CH * 230400;
    __hip_bfloat16* act1 = (__hip_bfloat16*)(ws);
    __hip_bfloat16* act2 = (__hip_bfloat16*)(ws + szA1);
    __hip_bfloat16* act3 = (__hip_bfloat16*)(ws + szA1 + szA2);
    float* pooled        = (float*)(ws + szA1 + szA2 + szA3);
    __hip_bfloat16* W2   = (__hip_bfloat16*)(ws + szA1 + szA2 + szA3 + SZ_POOL);
    __hip_bfloat16* W3   = (__hip_bfloat16*)((char*)W2 + SZ_W2);
    __hip_bfloat16* W4   = (__hip_bfloat16*)((char*)W3 + SZ_W3);
    float* bn            = (float*)((char*)W4 + SZ_W4);

    PrepArgs pa;
    pa.w2 = w2; pa.w3 = w3; pa.w4 = w4;
    pa.g1 = (const float*)d_in[13]; pa.b1 = (const float*)d_in[14];
    pa.m1 = (const float*)d_in[15]; pa.v1 = (const float*)d_in[16];
    pa.g2 = (const float*)d_in[17]; pa.b2 = (const float*)d_in[18];
    pa.m2 = (const float*)d_in[19]; pa.v2 = (const float*)d_in[20];
    pa.g3 = (const float*)d_in[21]; pa.b3 = (const float*)d_in[22];
    pa.m3 = (const float*)d_in[23]; pa.v3 = (const float*)d_in[24];
    pa.g4 = (const float*)d_in[25]; pa.b4 = (const float*)d_in[26];
    pa.m4 = (const float*)d_in[27]; pa.v4 = (const float*)d_in[28];
    pa.W2 = W2; pa.W3 = W3; pa.W4 = W4; pa.bn = bn;

    prep_k<<<938, 256, 0, stream>>>(pa);
    for (int c = 0; c < NCHUNK; ++c) {
        int b0 = c * CH;
        deform_k<<<CH, 256, 0, stream>>>(x, w_off, b_off, w_dcn, b_dcn, bn,
                                         act1, act2, act3, pooled, b0);
        conv_k<32, 64, false><<<dim3(7, CH), 128, 0, stream>>>(
            act1, W2, b2, bn + 64, bn + 128, act2, nullptr, b0, CH);
        conv_k<64, 128, false><<<dim3(7, CH), 128, 0, stream>>>(
            act2, W3, b3, bn + 192, bn + 320, act3, nullptr, b0, CH);
        conv_k<128, 128, true><<<dim3(7, CH), 128, 0, stream>>>(
            act3, W4, b4, bn + 448, bn + 576, nullptr, pooled, b0, CH);
    }
    head_k<<<256, 256, 0, stream>>>(pooled, w_fc, b_fc, (float*)d_out);
}

// Round 13
// 625.573 us; speedup vs baseline: 1.1025x; 1.0359x over previous
//
#include <hip/hip_runtime.h>
#include <hip/hip_bf16.h>

typedef __bf16 bf16x8 __attribute__((ext_vector_type(8)));
typedef float  f32x4  __attribute__((ext_vector_type(4)));

#define BN_EPS 1e-5f

// Per-image activation bytes (NHWC, padded 30x30):
constexpr size_t ACT_PER_IMG = 57600 + 115200 + 230400;      // 403200
constexpr size_t SZ_POOL = (size_t)1024 * 128 * 4;
constexpr size_t SZ_W2   = (size_t)9 * 64 * 32 * 2;
constexpr size_t SZ_W3   = (size_t)9 * 128 * 64 * 2;
constexpr size_t SZ_W4   = (size_t)9 * 128 * 128 * 2;
constexpr size_t SZ_BN   = 704 * 4;
constexpr size_t SZ_FIXED = SZ_POOL + SZ_W2 + SZ_W3 + SZ_W4 + SZ_BN;

__device__ __forceinline__ unsigned pack2(float a, float b) {
    __hip_bfloat162 h = __float22bfloat162_rn(make_float2(a, b));
    union { __hip_bfloat162 h2; unsigned u; } u;
    u.h2 = h;
    return u.u;
}

// ---------------- prep: weight transform to MFMA-fragment order + BN fold ----
// Fragment order: W'[s][nb][lane][e] -> a wave's B-frag load is 1KB contiguous.
struct PrepArgs {
    const float *w2, *w3, *w4;
    const float *g1, *b1, *m1, *v1;
    const float *g2, *b2, *m2, *v2;
    const float *g3, *b3, *m3, *v3;
    const float *g4, *b4, *m4, *v4;
    __hip_bfloat16 *W2, *W3, *W4;
    float *bn;
};

__global__ __launch_bounds__(256) void prep_k(PrepArgs a) {
    int idx = blockIdx.x * 256 + threadIdx.x;
    if (idx < 18432) {            // W2: CIN=32 (KC=1), COUT=64 (NB=4)
        int e = idx & 7, lane = (idx >> 3) & 63, r = idx >> 9;
        int nb = r & 3, t = r >> 2;
        int o = nb * 16 + (lane & 15);
        int i = (lane >> 4) * 8 + e;
        a.W2[idx] = __float2bfloat16(a.w2[(o * 32 + i) * 9 + t]);
        return;
    }
    idx -= 18432;
    if (idx < 73728) {            // W3: CIN=64 (KC=2), COUT=128 (NB=8)
        int e = idx & 7, lane = (idx >> 3) & 63, r = idx >> 9;
        int nb = r & 7, s = r >> 3;
        int kc = s & 1, t = s >> 1;
        int o = nb * 16 + (lane & 15);
        int i = kc * 32 + (lane >> 4) * 8 + e;
        a.W3[idx] = __float2bfloat16(a.w3[(o * 64 + i) * 9 + t]);
        return;
    }
    idx -= 73728;
    if (idx < 147456) {           // W4: CIN=128 (KC=4), COUT=128 (NB=8)
        int e = idx & 7, lane = (idx >> 3) & 63, r = idx >> 9;
        int nb = r & 7, s = r >> 3;
        int kc = s & 3, t = s >> 2;
        int o = nb * 16 + (lane & 15);
        int i = kc * 32 + (lane >> 4) * 8 + e;
        a.W4[idx] = __float2bfloat16(a.w4[(o * 128 + i) * 9 + t]);
        return;
    }
    idx -= 147456;
    if (idx < 352) {
        const float *g, *bb, *mm, *vv; int c, so, cn;
        if (idx < 32)       { g = a.g1; bb = a.b1; mm = a.m1; vv = a.v1; c = idx;       so = 0;   cn = 32;  }
        else if (idx < 96)  { g = a.g2; bb = a.b2; mm = a.m2; vv = a.v2; c = idx - 32;  so = 64;  cn = 64;  }
        else if (idx < 224) { g = a.g3; bb = a.b3; mm = a.m3; vv = a.v3; c = idx - 96;  so = 192; cn = 128; }
        else                { g = a.g4; bb = a.b4; mm = a.m4; vv = a.v4; c = idx - 224; so = 448; cn = 128; }
        float s = g[c] * rsqrtf(vv[c] + BN_EPS);
        a.bn[so + c] = s;
        a.bn[so + cn + c] = bb[c] - mm[c] * s;
    }
}

// ---------------- kernel 1: offsets + deform sample + DCN + BN1 ----------------
__global__ __launch_bounds__(256) void deform_k(
    const float* __restrict__ x, const float* __restrict__ w_off,
    const float* __restrict__ b_off, const float* __restrict__ w_dcn,
    const float* __restrict__ b_dcn, const float* __restrict__ bn,
    __hip_bfloat16* __restrict__ act1, __hip_bfloat16* __restrict__ act2,
    __hip_bfloat16* __restrict__ act3, float* __restrict__ pooled, int b0)
{
    const int lb = blockIdx.x;
    const int b  = b0 + lb;
    const int tid = threadIdx.x;
    __shared__ float xp[900];
    __shared__ float sw[564];
    float* swo = sw;
    float* sbo = sw + 162;
    float* swd = sw + 180;
    float* sbd = sw + 468;
    float* ss1 = sw + 500;
    float* ssh = sw + 532;

    for (int i = tid; i < 900; i += 256) {
        int y = i / 30, xc = i % 30;
        float v = 0.f;
        if (y >= 1 && y <= 28 && xc >= 1 && xc <= 28)
            v = x[(size_t)b * 784 + (y - 1) * 28 + (xc - 1)];
        xp[i] = v;
    }
    for (int i = tid; i < 564; i += 256) {
        float v;
        if (i < 162)      v = w_off[i];
        else if (i < 180) v = b_off[i - 162];
        else if (i < 468) v = w_dcn[i - 180];
        else if (i < 500) v = b_dcn[i - 468];
        else if (i < 532) v = bn[i - 500];
        else              v = bn[32 + (i - 532)];
        sw[i] = v;
    }
    if (tid < 128) pooled[b * 128 + tid] = 0.f;
    __syncthreads();

    for (int p = tid; p < 784; p += 256) {
        int y = p / 28, xx = p % 28;
        float off[18];
        #pragma unroll
        for (int o = 0; o < 18; o++) off[o] = sbo[o];
        #pragma unroll
        for (int ty = 0; ty < 3; ty++)
            #pragma unroll
            for (int tx = 0; tx < 3; tx++) {
                float xv = xp[(y + ty) * 30 + (xx + tx)];
                int tap = ty * 3 + tx;
                #pragma unroll
                for (int o = 0; o < 18; o++) off[o] = fmaf(xv, swo[o * 9 + tap], off[o]);
            }
        float s[9];
        #pragma unroll
        for (int j = 0; j < 9; j++) {
            float py = (float)y + (float)(j / 3 - 1) + off[2 * j];
            float px = (float)xx + (float)(j % 3 - 1) + off[2 * j + 1];
            float y0 = floorf(py), x0 = floorf(px);
            float wy1 = py - y0, wx1 = px - x0;
            float wy0 = 1.f - wy1, wx0 = 1.f - wx1;
            float acc = 0.f;
            #pragma unroll
            for (int cy = 0; cy < 2; cy++)
                #pragma unroll
                for (int cx = 0; cx < 2; cx++) {
                    float yy = y0 + (float)cy, xf = x0 + (float)cx;
                    bool valid = (yy >= 0.f) && (yy <= 27.f) && (xf >= 0.f) && (xf <= 27.f);
                    int yc = (int)fminf(fmaxf(yy, 0.f), 27.f);
                    int xc = (int)fminf(fmaxf(xf, 0.f), 27.f);
                    float g = valid ? xp[(yc + 1) * 30 + (xc + 1)] : 0.f;
                    float w = (cy ? wy1 : wy0) * (cx ? wx1 : wx0);
                    acc = fmaf(g, w, acc);
                }
            s[j] = acc;
        }
        size_t base = ((size_t)lb * 900 + (size_t)(y + 1) * 30 + (xx + 1)) * 32;
        #pragma unroll
        for (int c0 = 0; c0 < 32; c0 += 8) {
            float h[8];
            #pragma unroll
            for (int ci = 0; ci < 8; ci++) {
                int c = c0 + ci;
                float hv = sbd[c];
                #pragma unroll
                for (int j = 0; j < 9; j++) hv = fmaf(s[j], swd[c * 9 + j], hv);
                h[ci] = hv * ss1[c] + ssh[c];
            }
            uint4 q;
            q.x = pack2(h[0], h[1]); q.y = pack2(h[2], h[3]);
            q.z = pack2(h[4], h[5]); q.w = pack2(h[6], h[7]);
            *reinterpret_cast<uint4*>(&act1[base + c0]) = q;
        }
    }

    for (int i = tid; i < 116; i += 256) {
        int py, px;
        if (i < 30)      { py = 0;          px = i; }
        else if (i < 60) { py = 29;         px = i - 30; }
        else if (i < 88) { py = i - 60 + 1; px = 0; }
        else             { py = i - 88 + 1; px = 29; }
        size_t pix = (size_t)lb * 900 + (size_t)py * 30 + px;
        uint4 z = {0, 0, 0, 0};
        uint4* p1 = reinterpret_cast<uint4*>(&act1[pix * 32]);
        #pragma unroll
        for (int k = 0; k < 4; k++) p1[k] = z;
        uint4* p2 = reinterpret_cast<uint4*>(&act2[pix * 64]);
        #pragma unroll
        for (int k = 0; k < 8; k++) p2[k] = z;
        uint4* p3 = reinterpret_cast<uint4*>(&act3[pix * 128]);
        #pragma unroll
        for (int k = 0; k < 16; k++) p3[k] = z;
    }
}

// ---------------- shared conv helpers ----------------
template<int CIN>
__device__ __forceinline__ int swz(int ofs) {
    if constexpr (CIN == 128) return (ofs >> 4) & 0x70;      // bits 8-10 -> 4-6
    else if constexpr (CIN == 64) return (ofs >> 3) & 0x70;  // bits 7-9  -> 4-6
    else return (ofs >> 2) & 0x30;                           // bits 6-7  -> 4-5
}

// Weight fragment load, fragment-order layout: contiguous 1KB per frag per wave.
// ng = index of this wave's n-group of NFW frags.
template<int COUT, int NFW>
__device__ __forceinline__ void loadWf(const __hip_bfloat16* __restrict__ Wt,
                                       int s, int ng, int lane, bf16x8 (&bf)[NFW]) {
    constexpr int NB = COUT / 16;
    #pragma unroll
    for (int nf = 0; nf < NFW; ++nf)
        bf[nf] = *reinterpret_cast<const bf16x8*>(
            Wt + (((size_t)s * NB + ng * NFW + nf) * 64 + lane) * 8);
}

// ============================================================================
// Variant A (r11 winner for CIN=128): 4 waves = (mhalf x nhalf), MFW=4/3,
// NFW=COUT/32, 3-deep statically-rotated pipeline. VGPR ~104, no spill.
// ============================================================================
template<int CIN, int MFW>
__device__ __forceinline__ void loadAf4(const __hip_bfloat16* tile,
                                        int s, const int (&pr)[4], const int (&pc)[4],
                                        int kg, bf16x8 (&af)[MFW]) {
    constexpr int KC = CIN / 32;
    int t = s / KC, kc = (s % KC) * 32;
    int ty = t / 3, tx = t % 3;
    #pragma unroll
    for (int mf = 0; mf < MFW; ++mf) {
        int pix = (pr[mf] + ty) * 30 + (pc[mf] + tx);
        int ba = (pix * CIN + kc + kg * 8) * 2;
        ba ^= swz<CIN>(ba);
        af[mf] = *reinterpret_cast<const bf16x8*>(
            reinterpret_cast<const char*>(tile) + ba);
    }
}

template<int MFW, int NFW>
__device__ __forceinline__ void mstep(const bf16x8 (&af)[MFW], const bf16x8 (&wf)[NFW],
                                      f32x4 (&acc)[MFW][NFW]) {
    #pragma unroll
    for (int mf = 0; mf < MFW; ++mf)
        #pragma unroll
        for (int nf = 0; nf < NFW; ++nf)
            acc[mf][nf] = __builtin_amdgcn_mfma_f32_16x16x32_bf16(
                af[mf], wf[nf], acc[mf][nf], 0, 0, 0);
}

template<int CIN, int COUT, bool POOL, int MFW>
__device__ __forceinline__ void conv_body4(
    const __hip_bfloat16* tile,
    const __hip_bfloat16* __restrict__ Wt,
    const float* __restrict__ bconv, const float* __restrict__ bnS,
    const float* __restrict__ bnB, __hip_bfloat16* __restrict__ aout,
    float* __restrict__ pooled, int lb, int gb, int rg, int lane, int mhalf, int nhalf)
{
    constexpr int KC  = CIN / 32;
    constexpr int NS  = 9 * KC;
    constexpr int NFW = COUT / 32;
    const int l15 = lane & 15, kg = lane >> 4;
    const int nbase = nhalf * (NFW * 16) + l15;

    int pr[4], pc[4];
    #pragma unroll
    for (int mf = 0; mf < MFW; ++mf) {
        int m = (mhalf * 4 + mf) * 16 + l15;
        pr[mf] = m / 28;
        pc[mf] = m % 28;
    }

    f32x4 acc[MFW][NFW] = {};
    bf16x8 wA[NFW], wB[NFW], wC[NFW];
    bf16x8 aA[MFW], aB[MFW], aC[MFW];

    loadWf<COUT, NFW>(Wt, 0, nhalf, lane, wA);
    loadAf4<CIN, MFW>(tile, 0, pr, pc, kg, aA);
    loadWf<COUT, NFW>(Wt, 1, nhalf, lane, wB);
    loadAf4<CIN, MFW>(tile, 1, pr, pc, kg, aB);

    #pragma unroll
    for (int s = 0; s < NS; s += 3) {
        if (s + 2 < NS) {
            loadWf<COUT, NFW>(Wt, s + 2, nhalf, lane, wC);
            loadAf4<CIN, MFW>(tile, s + 2, pr, pc, kg, aC);
        }
        __builtin_amdgcn_sched_barrier(0);
        mstep<MFW, NFW>(aA, wA, acc);
        if (s + 3 < NS) {
            loadWf<COUT, NFW>(Wt, s + 3, nhalf, lane, wA);
            loadAf4<CIN, MFW>(tile, s + 3, pr, pc, kg, aA);
        }
        __builtin_amdgcn_sched_barrier(0);
        mstep<MFW, NFW>(aB, wB, acc);
        if (s + 4 < NS) {
            loadWf<COUT, NFW>(Wt, s + 4, nhalf, lane, wB);
            loadAf4<CIN, MFW>(tile, s + 4, pr, pc, kg, aB);
        }
        __builtin_amdgcn_sched_barrier(0);
        if (s + 2 < NS) mstep<MFW, NFW>(aC, wC, acc);
    }

    if constexpr (!POOL) {
        #pragma unroll
        for (int mf = 0; mf < MFW; ++mf) {
            #pragma unroll
            for (int nf = 0; nf < NFW; ++nf) {
                int n = nbase + nf * 16;
                float bc = bconv[n], sc = bnS[n], sh = bnB[n];
                #pragma unroll
                for (int r = 0; r < 4; r++) {
                    int m = (mhalf * 4 + mf) * 16 + kg * 4 + r;
                    float y = acc[mf][nf][r] + bc;
                    y = fmaxf(y, 0.f);
                    y = y * sc + sh;
                    int oy = m / 28, ox = m % 28;
                    aout[((size_t)lb * 900 + (size_t)(rg * 4 + oy + 1) * 30 + (ox + 1)) * COUT + n]
                        = __float2bfloat16(y);
                }
            }
        }
    } else {
        #pragma unroll
        for (int nf = 0; nf < NFW; ++nf) {
            int n = nbase + nf * 16;
            float bc = bconv[n], sc = bnS[n], sh = bnB[n];
            float ps = 0.f;
            #pragma unroll
            for (int mf = 0; mf < MFW; ++mf)
                #pragma unroll
                for (int r = 0; r < 4; r++) {
                    float y = acc[mf][nf][r] + bc;
                    y = fmaxf(y, 0.f);
                    ps += y * sc + sh;
                }
            ps += __shfl_xor(ps, 16, 64);
            ps += __shfl_xor(ps, 32, 64);
            if (lane < 16) atomicAdd(&pooled[gb * COUT + n], ps);
        }
    }
}

template<int CIN, int COUT, bool POOL>
__global__ __launch_bounds__(256, 2) void conv_k4(
    const __hip_bfloat16* __restrict__ ain,
    const __hip_bfloat16* __restrict__ Wt,
    const float* __restrict__ bconv,
    const float* __restrict__ bnS,
    const float* __restrict__ bnB,
    __hip_bfloat16* __restrict__ aout,
    float* __restrict__ pooled, int b0, int nimg)
{
    __shared__ __align__(16) __hip_bfloat16 tile[180 * CIN];
    const int tid = threadIdx.x;
    const int lane = tid & 63;
    const int wv = tid >> 6;
    const int mhalf = wv >> 1, nhalf = wv & 1;

    int rg, lb;
    {
        int flat = blockIdx.x + 7 * blockIdx.y;
        if ((nimg & 7) == 0) {
            int xcd = flat & 7, idx = flat >> 3;
            lb = xcd * (nimg >> 3) + idx / 7;
            rg = idx % 7;
        } else {
            rg = blockIdx.x; lb = blockIdx.y;
        }
    }

    const char* src = reinterpret_cast<const char*>(
        ain + ((size_t)lb * 900 + (size_t)rg * 120) * CIN);
    constexpr int TB = 180 * CIN * 2;
    for (int ofs = tid * 16; ofs < TB; ofs += 4096) {
        uint4 v = *reinterpret_cast<const uint4*>(src + ofs);
        *reinterpret_cast<uint4*>(reinterpret_cast<char*>(tile) + (ofs ^ swz<CIN>(ofs))) = v;
    }
    __syncthreads();

    if (mhalf == 0)
        conv_body4<CIN, COUT, POOL, 4>(tile, Wt, bconv, bnS, bnB, aout, pooled,
                                       lb, b0 + lb, rg, lane, mhalf, nhalf);
    else
        conv_body4<CIN, COUT, POOL, 3>(tile, Wt, bconv, bnS, bnB, aout, pooled,
                                       lb, b0 + lb, rg, lane, mhalf, nhalf);
}

// ============================================================================
// Variant B (r12 winner for conv2/conv3): 2 waves partition N only, MFW=7,
// NFW=COUT/32; halves per-block weight traffic. 2-deep pipeline.
// ============================================================================
template<int CIN>
__device__ __forceinline__ void loadAf7(const __hip_bfloat16* tile,
                                        int s, const int (&pr)[7], const int (&pc)[7],
                                        int kg, bf16x8 (&af)[7]) {
    constexpr int KC = CIN / 32;
    int t = s / KC, kc = (s % KC) * 32;
    int ty = t / 3, tx = t % 3;
    #pragma unroll
    for (int mf = 0; mf < 7; ++mf) {
        int pix = (pr[mf] + ty) * 30 + (pc[mf] + tx);
        int ba = (pix * CIN + kc + kg * 8) * 2;
        ba ^= swz<CIN>(ba);
        af[mf] = *reinterpret_cast<const bf16x8*>(
            reinterpret_cast<const char*>(tile) + ba);
    }
}

template<int NFW>
__device__ __forceinline__ void mstep7(const bf16x8 (&af)[7], const bf16x8 (&wf)[NFW],
                                       f32x4 (&acc)[7][NFW]) {
    #pragma unroll
    for (int mf = 0; mf < 7; ++mf)
        #pragma unroll
        for (int nf = 0; nf < NFW; ++nf)
            acc[mf][nf] = __builtin_amdgcn_mfma_f32_16x16x32_bf16(
                af[mf], wf[nf], acc[mf][nf], 0, 0, 0);
}

template<int CIN, int COUT, bool POOL>
__device__ __forceinline__ void conv_body2(
    const __hip_bfloat16* tile,
    const __hip_bfloat16* __restrict__ Wt,
    const float* __restrict__ bconv, const float* __restrict__ bnS,
    const float* __restrict__ bnB, __hip_bfloat16* __restrict__ aout,
    float* __restrict__ pooled, int lb, int gb, int rg, int lane, int nq)
{
    constexpr int KC  = CIN / 32;
    constexpr int NS  = 9 * KC;
    constexpr int NFW = COUT / 32;
    const int l15 = lane & 15, kg = lane >> 4;
    const int nbase = nq * (NFW * 16) + l15;

    int pr[7], pc[7];
    #pragma unroll
    for (int mf = 0; mf < 7; ++mf) {
        int m = mf * 16 + l15;
        pr[mf] = m / 28;
        pc[mf] = m % 28;
    }

    f32x4 acc[7][NFW] = {};
    bf16x8 wA[NFW], wB[NFW], aA[7], aB[7];

    loadWf<COUT, NFW>(Wt, 0, nq, lane, wA);
    loadAf7<CIN>(tile, 0, pr, pc, kg, aA);
    loadWf<COUT, NFW>(Wt, 1, nq, lane, wB);
    loadAf7<CIN>(tile, 1, pr, pc, kg, aB);

    #pragma unroll
    for (int s = 0; s < NS; s += 2) {
        __builtin_amdgcn_sched_barrier(0);
        mstep7<NFW>(aA, wA, acc);
        if (s + 2 < NS) {
            loadWf<COUT, NFW>(Wt, s + 2, nq, lane, wA);
            loadAf7<CIN>(tile, s + 2, pr, pc, kg, aA);
        }
        __builtin_amdgcn_sched_barrier(0);
        if (s + 1 < NS) {
            mstep7<NFW>(aB, wB, acc);
            if (s + 3 < NS) {
                loadWf<COUT, NFW>(Wt, s + 3, nq, lane, wB);
                loadAf7<CIN>(tile, s + 3, pr, pc, kg, aB);
            }
        }
    }

    if constexpr (!POOL) {
        #pragma unroll
        for (int mf = 0; mf < 7; ++mf) {
            #pragma unroll
            for (int nf = 0; nf < NFW; ++nf) {
                int n = nbase + nf * 16;
                float bc = bconv[n], sc = bnS[n], sh = bnB[n];
                #pragma unroll
                for (int r = 0; r < 4; r++) {
                    int m = mf * 16 + kg * 4 + r;
                    float y = acc[mf][nf][r] + bc;
                    y = fmaxf(y, 0.f);
                    y = y * sc + sh;
                    int oy = m / 28, ox = m % 28;
                    aout[((size_t)lb * 900 + (size_t)(rg * 4 + oy + 1) * 30 + (ox + 1)) * COUT + n]
                        = __float2bfloat16(y);
                }
            }
        }
    } else {
        #pragma unroll
        for (int nf = 0; nf < NFW; ++nf) {
            int n = nbase + nf * 16;
            float bc = bconv[n], sc = bnS[n], sh = bnB[n];
            float ps = 0.f;
            #pragma unroll
            for (int mf = 0; mf < 7; ++mf)
                #pragma unroll
                for (int r = 0; r < 4; r++) {
                    float y = acc[mf][nf][r] + bc;
                    y = fmaxf(y, 0.f);
                    ps += y * sc + sh;
                }
            ps += __shfl_xor(ps, 16, 64);
            ps += __shfl_xor(ps, 32, 64);
            if (lane < 16) atomicAdd(&pooled[gb * COUT + n], ps);
        }
    }
}

template<int CIN, int COUT, bool POOL>
__global__ __launch_bounds__(128, 2) void conv_k2(
    const __hip_bfloat16* __restrict__ ain,
    const __hip_bfloat16* __restrict__ Wt,
    const float* __restrict__ bconv,
    const float* __restrict__ bnS,
    const float* __restrict__ bnB,
    __hip_bfloat16* __restrict__ aout,
    float* __restrict__ pooled, int b0, int nimg)
{
    __shared__ __align__(16) __hip_bfloat16 tile[180 * CIN];
    const int tid = threadIdx.x;
    const int lane = tid & 63;
    const int nq = tid >> 6;           // 0..1 — waves partition N only

    int rg, lb;
    {
        int flat = blockIdx.x + 7 * blockIdx.y;
        if ((nimg & 7) == 0) {
            int xcd = flat & 7, idx = flat >> 3;
            lb = xcd * (nimg >> 3) + idx / 7;
            rg = idx % 7;
        } else {
            rg = blockIdx.x; lb = blockIdx.y;
        }
    }

    const char* src = reinterpret_cast<const char*>(
        ain + ((size_t)lb * 900 + (size_t)rg * 120) * CIN);
    constexpr int TB = 180 * CIN * 2;
    for (int ofs = tid * 16; ofs < TB; ofs += 2048) {
        uint4 v = *reinterpret_cast<const uint4*>(src + ofs);
        *reinterpret_cast<uint4*>(reinterpret_cast<char*>(tile) + (ofs ^ swz<CIN>(ofs))) = v;
    }
    __syncthreads();

    conv_body2<CIN, COUT, POOL>(tile, Wt, bconv, bnS, bnB, aout, pooled,
                                lb, b0 + lb, rg, lane, nq);
}

// ---------------- head: mean-pool scale + FC + log-softmax ----------------
__global__ __launch_bounds__(256) void head_k(
    const float* __restrict__ pooled, const float* __restrict__ wfc,
    const float* __restrict__ bfc, float* __restrict__ out)
{
    int b = blockIdx.x * 4 + (threadIdx.x >> 6);
    int lane = threadIdx.x & 63;
    float m0 = pooled[b * 128 + lane] * (1.f / 784.f);
    float m1 = pooled[b * 128 + 64 + lane] * (1.f / 784.f);
    float lg[10];
    #pragma unroll
    for (int k = 0; k < 10; k++) {
        float p = m0 * wfc[k * 128 + lane] + m1 * wfc[k * 128 + 64 + lane];
        #pragma unroll
        for (int s2 = 32; s2 >= 1; s2 >>= 1) p += __shfl_xor(p, s2, 64);
        lg[k] = p + bfc[k];
    }
    float mx = lg[0];
    #pragma unroll
    for (int k = 1; k < 10; k++) mx = fmaxf(mx, lg[k]);
    float se = 0.f;
    #pragma unroll
    for (int k = 0; k < 10; k++) se += expf(lg[k] - mx);
    float lse = mx + logf(se);
    #pragma unroll
    for (int k = 0; k < 10; k++)
        if (lane == k) out[b * 10 + k] = lg[k] - lse;
}

// ---------------- launch ----------------
extern "C" void kernel_launch(void* const* d_in, const int* in_sizes, int n_in,
                              void* d_out, int out_size, void* d_ws, size_t ws_size,
                              hipStream_t stream) {
    (void)in_sizes; (void)n_in; (void)out_size;
    const float* x     = (const float*)d_in[0];
    const float* w_off = (const float*)d_in[1];
    const float* b_off = (const float*)d_in[2];
    const float* w_dcn = (const float*)d_in[3];
    const float* b_dcn = (const float*)d_in[4];
    const float* w2    = (const float*)d_in[5];
    const float* b2    = (const float*)d_in[6];
    const float* w3    = (const float*)d_in[7];
    const float* b3    = (const float*)d_in[8];
    const float* w4    = (const float*)d_in[9];
    const float* b4    = (const float*)d_in[10];
    const float* w_fc  = (const float*)d_in[11];
    const float* b_fc  = (const float*)d_in[12];

    int CH = 256;
    while (CH > 1 && (size_t)CH * ACT_PER_IMG + SZ_FIXED > ws_size) CH >>= 1;
    const int NCHUNK = 1024 / CH;

    char* ws = (char*)d_ws;
    const size_t szA1 = (size_t)CH * 57600;
    const size_t szA2 = (size_t)CH * 115200;
    const size_t szA3 = (size_t)CH * 230400;
    __hip_bfloat16* act1 = (__hip_bfloat16*)(ws);
    __hip_bfloat16* act2 = (__hip_bfloat16*)(ws + szA1);
    __hip_bfloat16* act3 = (__hip_bfloat16*)(ws + szA1 + szA2);
    float* pooled        = (float*)(ws + szA1 + szA2 + szA3);
    __hip_bfloat16* W2   = (__hip_bfloat16*)(ws + szA1 + szA2 + szA3 + SZ_POOL);
    __hip_bfloat16* W3   = (__hip_bfloat16*)((char*)W2 + SZ_W2);
    __hip_bfloat16* W4   = (__hip_bfloat16*)((char*)W3 + SZ_W3);
    float* bn            = (float*)((char*)W4 + SZ_W4);

    PrepArgs pa;
    pa.w2 = w2; pa.w3 = w3; pa.w4 = w4;
    pa.g1 = (const float*)d_in[13]; pa.b1 = (const float*)d_in[14];
    pa.m1 = (const float*)d_in[15]; pa.v1 = (const float*)d_in[16];
    pa.g2 = (const float*)d_in[17]; pa.b2 = (const float*)d_in[18];
    pa.m2 = (const float*)d_in[19]; pa.v2 = (const float*)d_in[20];
    pa.g3 = (const float*)d_in[21]; pa.b3 = (const float*)d_in[22];
    pa.m3 = (const float*)d_in[23]; pa.v3 = (const float*)d_in[24];
    pa.g4 = (const float*)d_in[25]; pa.b4 = (const float*)d_in[26];
    pa.m4 = (const float*)d_in[27]; pa.v4 = (const float*)d_in[28];
    pa.W2 = W2; pa.W3 = W3; pa.W4 = W4; pa.bn = bn;

    prep_k<<<938, 256, 0, stream>>>(pa);
    for (int c = 0; c < NCHUNK; ++c) {
        int b0 = c * CH;
        deform_k<<<CH, 256, 0, stream>>>(x, w_off, b_off, w_dcn, b_dcn, bn,
                                         act1, act2, act3, pooled, b0);
        conv_k2<32, 64, false><<<dim3(7, CH), 128, 0, stream>>>(
            act1, W2, b2, bn + 64, bn + 128, act2, nullptr, b0, CH);
        conv_k2<64, 128, false><<<dim3(7, CH), 128, 0, stream>>>(
            act2, W3, b3, bn + 192, bn + 320, act3, nullptr, b0, CH);
        conv_k4<128, 128, true><<<dim3(7, CH), 256, 0, stream>>>(
            act3, W4, b4, bn + 448, bn + 576, nullptr, pooled, b0, CH);
    }
    head_k<<<256, 256, 0, stream>>>(pooled, w_fc, b_fc, (float*)d_out);
}

// Round 14
// 624.817 us; speedup vs baseline: 1.1039x; 1.0012x over previous
//
#include <hip/hip_runtime.h>
#include <hip/hip_bf16.h>

typedef __bf16 bf16x8 __attribute__((ext_vector_type(8)));
typedef float  f32x4  __attribute__((ext_vector_type(4)));

#define BN_EPS 1e-5f

// Per-image activation bytes (NHWC, padded 30x30):
constexpr size_t ACT_PER_IMG = 57600 + 115200 + 230400;      // 403200
constexpr size_t SZ_POOL = (size_t)1024 * 128 * 4;
constexpr size_t SZ_W2   = (size_t)9 * 64 * 32 * 2;
constexpr size_t SZ_W3   = (size_t)9 * 128 * 64 * 2;
constexpr size_t SZ_W4   = (size_t)9 * 128 * 128 * 2;
constexpr size_t SZ_BN   = 704 * 4;
constexpr size_t SZ_FIXED = SZ_POOL + SZ_W2 + SZ_W3 + SZ_W4 + SZ_BN;

__device__ __forceinline__ unsigned pack2(float a, float b) {
    __hip_bfloat162 h = __float22bfloat162_rn(make_float2(a, b));
    union { __hip_bfloat162 h2; unsigned u; } u;
    u.h2 = h;
    return u.u;
}

// ---------------- prep: weight transform to MFMA-fragment order + BN fold ----
// Fragment order: W'[s][nb][lane][e] -> a wave's B-frag load is 1KB contiguous.
struct PrepArgs {
    const float *w2, *w3, *w4;
    const float *g1, *b1, *m1, *v1;
    const float *g2, *b2, *m2, *v2;
    const float *g3, *b3, *m3, *v3;
    const float *g4, *b4, *m4, *v4;
    __hip_bfloat16 *W2, *W3, *W4;
    float *bn;
};

__global__ __launch_bounds__(256) void prep_k(PrepArgs a) {
    int idx = blockIdx.x * 256 + threadIdx.x;
    if (idx < 18432) {            // W2: CIN=32 (KC=1), COUT=64 (NB=4)
        int e = idx & 7, lane = (idx >> 3) & 63, r = idx >> 9;
        int nb = r & 3, t = r >> 2;
        int o = nb * 16 + (lane & 15);
        int i = (lane >> 4) * 8 + e;
        a.W2[idx] = __float2bfloat16(a.w2[(o * 32 + i) * 9 + t]);
        return;
    }
    idx -= 18432;
    if (idx < 73728) {            // W3: CIN=64 (KC=2), COUT=128 (NB=8)
        int e = idx & 7, lane = (idx >> 3) & 63, r = idx >> 9;
        int nb = r & 7, s = r >> 3;
        int kc = s & 1, t = s >> 1;
        int o = nb * 16 + (lane & 15);
        int i = kc * 32 + (lane >> 4) * 8 + e;
        a.W3[idx] = __float2bfloat16(a.w3[(o * 64 + i) * 9 + t]);
        return;
    }
    idx -= 73728;
    if (idx < 147456) {           // W4: CIN=128 (KC=4), COUT=128 (NB=8)
        int e = idx & 7, lane = (idx >> 3) & 63, r = idx >> 9;
        int nb = r & 7, s = r >> 3;
        int kc = s & 3, t = s >> 2;
        int o = nb * 16 + (lane & 15);
        int i = kc * 32 + (lane >> 4) * 8 + e;
        a.W4[idx] = __float2bfloat16(a.w4[(o * 128 + i) * 9 + t]);
        return;
    }
    idx -= 147456;
    if (idx < 352) {
        const float *g, *bb, *mm, *vv; int c, so, cn;
        if (idx < 32)       { g = a.g1; bb = a.b1; mm = a.m1; vv = a.v1; c = idx;       so = 0;   cn = 32;  }
        else if (idx < 96)  { g = a.g2; bb = a.b2; mm = a.m2; vv = a.v2; c = idx - 32;  so = 64;  cn = 64;  }
        else if (idx < 224) { g = a.g3; bb = a.b3; mm = a.m3; vv = a.v3; c = idx - 96;  so = 192; cn = 128; }
        else                { g = a.g4; bb = a.b4; mm = a.m4; vv = a.v4; c = idx - 224; so = 448; cn = 128; }
        float s = g[c] * rsqrtf(vv[c] + BN_EPS);
        a.bn[so + c] = s;
        a.bn[so + cn + c] = bb[c] - mm[c] * s;
    }
}

// ---------------- kernel 1: offsets + deform sample + DCN + BN1 ----------------
// Grid (4, CH): each block handles a quarter (196 px) of one image -> 4 blocks/CU
// (was 1 block/CU: latency-bound bilinear gathers with no TLP to hide them).
__global__ __launch_bounds__(256) void deform_k(
    const float* __restrict__ x, const float* __restrict__ w_off,
    const float* __restrict__ b_off, const float* __restrict__ w_dcn,
    const float* __restrict__ b_dcn, const float* __restrict__ bn,
    __hip_bfloat16* __restrict__ act1, __hip_bfloat16* __restrict__ act2,
    __hip_bfloat16* __restrict__ act3, float* __restrict__ pooled, int b0)
{
    const int q  = blockIdx.x;        // quarter 0..3
    const int lb = blockIdx.y;
    const int b  = b0 + lb;
    const int tid = threadIdx.x;
    __shared__ float xp[900];
    __shared__ float sw[564];
    float* swo = sw;
    float* sbo = sw + 162;
    float* swd = sw + 180;
    float* sbd = sw + 468;
    float* ss1 = sw + 500;
    float* ssh = sw + 532;

    for (int i = tid; i < 900; i += 256) {
        int y = i / 30, xc = i % 30;
        float v = 0.f;
        if (y >= 1 && y <= 28 && xc >= 1 && xc <= 28)
            v = x[(size_t)b * 784 + (y - 1) * 28 + (xc - 1)];
        xp[i] = v;
    }
    for (int i = tid; i < 564; i += 256) {
        float v;
        if (i < 162)      v = w_off[i];
        else if (i < 180) v = b_off[i - 162];
        else if (i < 468) v = w_dcn[i - 180];
        else if (i < 500) v = b_dcn[i - 468];
        else if (i < 532) v = bn[i - 500];
        else              v = bn[32 + (i - 532)];
        sw[i] = v;
    }
    if (q == 0 && tid < 128) pooled[b * 128 + tid] = 0.f;
    __syncthreads();

    if (tid < 196) {
        int p = q * 196 + tid;
        int y = p / 28, xx = p % 28;
        float off[18];
        #pragma unroll
        for (int o = 0; o < 18; o++) off[o] = sbo[o];
        #pragma unroll
        for (int ty = 0; ty < 3; ty++)
            #pragma unroll
            for (int tx = 0; tx < 3; tx++) {
                float xv = xp[(y + ty) * 30 + (xx + tx)];
                int tap = ty * 3 + tx;
                #pragma unroll
                for (int o = 0; o < 18; o++) off[o] = fmaf(xv, swo[o * 9 + tap], off[o]);
            }
        float s[9];
        #pragma unroll
        for (int j = 0; j < 9; j++) {
            float py = (float)y + (float)(j / 3 - 1) + off[2 * j];
            float px = (float)xx + (float)(j % 3 - 1) + off[2 * j + 1];
            float y0 = floorf(py), x0 = floorf(px);
            float wy1 = py - y0, wx1 = px - x0;
            float wy0 = 1.f - wy1, wx0 = 1.f - wx1;
            float acc = 0.f;
            #pragma unroll
            for (int cy = 0; cy < 2; cy++)
                #pragma unroll
                for (int cx = 0; cx < 2; cx++) {
                    float yy = y0 + (float)cy, xf = x0 + (float)cx;
                    bool valid = (yy >= 0.f) && (yy <= 27.f) && (xf >= 0.f) && (xf <= 27.f);
                    int yc = (int)fminf(fmaxf(yy, 0.f), 27.f);
                    int xc = (int)fminf(fmaxf(xf, 0.f), 27.f);
                    float g = valid ? xp[(yc + 1) * 30 + (xc + 1)] : 0.f;
                    float w = (cy ? wy1 : wy0) * (cx ? wx1 : wx0);
                    acc = fmaf(g, w, acc);
                }
            s[j] = acc;
        }
        size_t base = ((size_t)lb * 900 + (size_t)(y + 1) * 30 + (xx + 1)) * 32;
        #pragma unroll
        for (int c0 = 0; c0 < 32; c0 += 8) {
            float h[8];
            #pragma unroll
            for (int ci = 0; ci < 8; ci++) {
                int c = c0 + ci;
                float hv = sbd[c];
                #pragma unroll
                for (int j = 0; j < 9; j++) hv = fmaf(s[j], swd[c * 9 + j], hv);
                h[ci] = hv * ss1[c] + ssh[c];
            }
            uint4 qv;
            qv.x = pack2(h[0], h[1]); qv.y = pack2(h[2], h[3]);
            qv.z = pack2(h[4], h[5]); qv.w = pack2(h[6], h[7]);
            *reinterpret_cast<uint4*>(&act1[base + c0]) = qv;
        }
    }

    // zero padded borders (116 = 4 quarters x 29)
    if (tid < 29) {
        int i = q * 29 + tid;
        int py, px;
        if (i < 30)      { py = 0;          px = i; }
        else if (i < 60) { py = 29;         px = i - 30; }
        else if (i < 88) { py = i - 60 + 1; px = 0; }
        else             { py = i - 88 + 1; px = 29; }
        size_t pix = (size_t)lb * 900 + (size_t)py * 30 + px;
        uint4 z = {0, 0, 0, 0};
        uint4* p1 = reinterpret_cast<uint4*>(&act1[pix * 32]);
        #pragma unroll
        for (int k = 0; k < 4; k++) p1[k] = z;
        uint4* p2 = reinterpret_cast<uint4*>(&act2[pix * 64]);
        #pragma unroll
        for (int k = 0; k < 8; k++) p2[k] = z;
        uint4* p3 = reinterpret_cast<uint4*>(&act3[pix * 128]);
        #pragma unroll
        for (int k = 0; k < 16; k++) p3[k] = z;
    }
}

// ---------------- conv 3x3: NWAVES waves partition N only, MFW=7 -------------
// Weight traffic per block per K-step = (COUT/16) frags total, split across
// waves with NO duplication (the r6-r11 m-split duplicated it 2x). Accumulator
// per wave = 7 x NFW x 4 VGPR; NFW = COUT/(16*NWAVES) chosen so acc=56 (no
// spill; r12's 128-thread NFW=4 variant spilled at the 128-VGPR cap).
template<int CIN>
__device__ __forceinline__ int swz(int ofs) {
    if constexpr (CIN == 128) return (ofs >> 4) & 0x70;      // bits 8-10 -> 4-6
    else if constexpr (CIN == 64) return (ofs >> 3) & 0x70;  // bits 7-9  -> 4-6
    else return (ofs >> 2) & 0x30;                           // bits 6-7  -> 4-5
}

template<int COUT, int NFW>
__device__ __forceinline__ void loadWf(const __hip_bfloat16* __restrict__ Wt,
                                       int s, int ng, int lane, bf16x8 (&bf)[NFW]) {
    constexpr int NB = COUT / 16;
    #pragma unroll
    for (int nf = 0; nf < NFW; ++nf)
        bf[nf] = *reinterpret_cast<const bf16x8*>(
            Wt + (((size_t)s * NB + ng * NFW + nf) * 64 + lane) * 8);
}

template<int CIN>
__device__ __forceinline__ void loadAf7(const __hip_bfloat16* tile,
                                        int s, const int (&pr)[7], const int (&pc)[7],
                                        int kg, bf16x8 (&af)[7]) {
    constexpr int KC = CIN / 32;
    int t = s / KC, kc = (s % KC) * 32;
    int ty = t / 3, tx = t % 3;
    #pragma unroll
    for (int mf = 0; mf < 7; ++mf) {
        int pix = (pr[mf] + ty) * 30 + (pc[mf] + tx);
        int ba = (pix * CIN + kc + kg * 8) * 2;
        ba ^= swz<CIN>(ba);
        af[mf] = *reinterpret_cast<const bf16x8*>(
            reinterpret_cast<const char*>(tile) + ba);
    }
}

template<int NFW>
__device__ __forceinline__ void mstep7(const bf16x8 (&af)[7], const bf16x8 (&wf)[NFW],
                                       f32x4 (&acc)[7][NFW]) {
    #pragma unroll
    for (int mf = 0; mf < 7; ++mf)
        #pragma unroll
        for (int nf = 0; nf < NFW; ++nf)
            acc[mf][nf] = __builtin_amdgcn_mfma_f32_16x16x32_bf16(
                af[mf], wf[nf], acc[mf][nf], 0, 0, 0);
}

template<int CIN, int COUT, int NWAVES, bool POOL>
__device__ __forceinline__ void conv_body(
    const __hip_bfloat16* tile,
    const __hip_bfloat16* __restrict__ Wt,
    const float* __restrict__ bconv, const float* __restrict__ bnS,
    const float* __restrict__ bnB, __hip_bfloat16* __restrict__ aout,
    float* __restrict__ pooled, int lb, int gb, int rg, int lane, int nq)
{
    constexpr int KC  = CIN / 32;
    constexpr int NS  = 9 * KC;                 // 9 / 18 / 36
    constexpr int NFW = COUT / (16 * NWAVES);   // 2 everywhere
    const int l15 = lane & 15, kg = lane >> 4;
    const int nbase = nq * (NFW * 16) + l15;

    int pr[7], pc[7];
    #pragma unroll
    for (int mf = 0; mf < 7; ++mf) {
        int m = mf * 16 + l15;
        pr[mf] = m / 28;
        pc[mf] = m % 28;
    }

    f32x4 acc[7][NFW] = {};
    bf16x8 wA[NFW], wB[NFW], aA[7], aB[7];

    loadWf<COUT, NFW>(Wt, 0, nq, lane, wA);
    loadAf7<CIN>(tile, 0, pr, pc, kg, aA);
    loadWf<COUT, NFW>(Wt, 1, nq, lane, wB);
    loadAf7<CIN>(tile, 1, pr, pc, kg, aB);

    #pragma unroll
    for (int s = 0; s < NS; s += 2) {
        __builtin_amdgcn_sched_barrier(0);
        mstep7<NFW>(aA, wA, acc);
        if (s + 2 < NS) {
            loadWf<COUT, NFW>(Wt, s + 2, nq, lane, wA);
            loadAf7<CIN>(tile, s + 2, pr, pc, kg, aA);
        }
        __builtin_amdgcn_sched_barrier(0);
        if (s + 1 < NS) {
            mstep7<NFW>(aB, wB, acc);
            if (s + 3 < NS) {
                loadWf<COUT, NFW>(Wt, s + 3, nq, lane, wB);
                loadAf7<CIN>(tile, s + 3, pr, pc, kg, aB);
            }
        }
    }

    if constexpr (!POOL) {
        #pragma unroll
        for (int mf = 0; mf < 7; ++mf) {
            #pragma unroll
            for (int nf = 0; nf < NFW; ++nf) {
                int n = nbase + nf * 16;
                float bc = bconv[n], sc = bnS[n], sh = bnB[n];
                #pragma unroll
                for (int r = 0; r < 4; r++) {
                    int m = mf * 16 + kg * 4 + r;
                    float y = acc[mf][nf][r] + bc;
                    y = fmaxf(y, 0.f);
                    y = y * sc + sh;
                    int oy = m / 28, ox = m % 28;
                    aout[((size_t)lb * 900 + (size_t)(rg * 4 + oy + 1) * 30 + (ox + 1)) * COUT + n]
                        = __float2bfloat16(y);
                }
            }
        }
    } else {
        #pragma unroll
        for (int nf = 0; nf < NFW; ++nf) {
            int n = nbase + nf * 16;
            float bc = bconv[n], sc = bnS[n], sh = bnB[n];
            float ps = 0.f;
            #pragma unroll
            for (int mf = 0; mf < 7; ++mf)
                #pragma unroll
                for (int r = 0; r < 4; r++) {
                    float y = acc[mf][nf][r] + bc;
                    y = fmaxf(y, 0.f);
                    ps += y * sc + sh;
                }
            ps += __shfl_xor(ps, 16, 64);
            ps += __shfl_xor(ps, 32, 64);
            if (lane < 16) atomicAdd(&pooled[gb * COUT + n], ps);
        }
    }
}

template<int CIN, int COUT, int NWAVES, bool POOL>
__global__ __launch_bounds__(NWAVES * 64, 2) void conv_k(
    const __hip_bfloat16* __restrict__ ain,
    const __hip_bfloat16* __restrict__ Wt,
    const float* __restrict__ bconv,
    const float* __restrict__ bnS,
    const float* __restrict__ bnB,
    __hip_bfloat16* __restrict__ aout,
    float* __restrict__ pooled, int b0, int nimg)
{
    __shared__ __align__(16) __hip_bfloat16 tile[180 * CIN];
    const int tid = threadIdx.x;
    const int lane = tid & 63;
    const int nq = tid >> 6;           // wave index: partitions N only

    // XCD-aware block swizzle: keep one image's 7 row-groups on one XCD.
    int rg, lb;
    {
        int flat = blockIdx.x + 7 * blockIdx.y;
        if ((nimg & 7) == 0) {
            int xcd = flat & 7, idx = flat >> 3;
            lb = xcd * (nimg >> 3) + idx / 7;
            rg = idx % 7;
        } else {
            rg = blockIdx.x; lb = blockIdx.y;
        }
    }

    // stage 6 padded rows (rg*4 .. rg*4+5) x 30 x CIN, XOR-swizzled (reg-staged)
    const char* src = reinterpret_cast<const char*>(
        ain + ((size_t)lb * 900 + (size_t)rg * 120) * CIN);
    constexpr int TB = 180 * CIN * 2;
    constexpr int STEP = NWAVES * 64 * 16;
    for (int ofs = tid * 16; ofs < TB; ofs += STEP) {
        uint4 v = *reinterpret_cast<const uint4*>(src + ofs);
        *reinterpret_cast<uint4*>(reinterpret_cast<char*>(tile) + (ofs ^ swz<CIN>(ofs))) = v;
    }
    __syncthreads();

    conv_body<CIN, COUT, NWAVES, POOL>(tile, Wt, bconv, bnS, bnB, aout, pooled,
                                       lb, b0 + lb, rg, lane, nq);
}

// ---------------- head: mean-pool scale + FC + log-softmax ----------------
__global__ __launch_bounds__(256) void head_k(
    const float* __restrict__ pooled, const float* __restrict__ wfc,
    const float* __restrict__ bfc, float* __restrict__ out)
{
    int b = blockIdx.x * 4 + (threadIdx.x >> 6);
    int lane = threadIdx.x & 63;
    float m0 = pooled[b * 128 + lane] * (1.f / 784.f);
    float m1 = pooled[b * 128 + 64 + lane] * (1.f / 784.f);
    float lg[10];
    #pragma unroll
    for (int k = 0; k < 10; k++) {
        float p = m0 * wfc[k * 128 + lane] + m1 * wfc[k * 128 + 64 + lane];
        #pragma unroll
        for (int s2 = 32; s2 >= 1; s2 >>= 1) p += __shfl_xor(p, s2, 64);
        lg[k] = p + bfc[k];
    }
    float mx = lg[0];
    #pragma unroll
    for (int k = 1; k < 10; k++) mx = fmaxf(mx, lg[k]);
    float se = 0.f;
    #pragma unroll
    for (int k = 0; k < 10; k++) se += expf(lg[k] - mx);
    float lse = mx + logf(se);
    #pragma unroll
    for (int k = 0; k < 10; k++)
        if (lane == k) out[b * 10 + k] = lg[k] - lse;
}

// ---------------- launch ----------------
extern "C" void kernel_launch(void* const* d_in, const int* in_sizes, int n_in,
                              void* d_out, int out_size, void* d_ws, size_t ws_size,
                              hipStream_t stream) {
    (void)in_sizes; (void)n_in; (void)out_size;
    const float* x     = (const float*)d_in[0];
    const float* w_off = (const float*)d_in[1];
    const float* b_off = (const float*)d_in[2];
    const float* w_dcn = (const float*)d_in[3];
    const float* b_dcn = (const float*)d_in[4];
    const float* w2    = (const float*)d_in[5];
    const float* b2    = (const float*)d_in[6];
    const float* w3    = (const float*)d_in[7];
    const float* b3    = (const float*)d_in[8];
    const float* w4    = (const float*)d_in[9];
    const float* b4    = (const float*)d_in[10];
    const float* w_fc  = (const float*)d_in[11];
    const float* b_fc  = (const float*)d_in[12];

    int CH = 256;
    while (CH > 1 && (size_t)CH * ACT_PER_IMG + SZ_FIXED > ws_size) CH >>= 1;
    const int NCHUNK = 1024 / CH;

    char* ws = (char*)d_ws;
    const size_t szA1 = (size_t)CH * 57600;
    const size_t szA2 = (size_t)CH * 115200;
    const size_t szA3 = (size_t)CH * 230400;
    __hip_bfloat16* act1 = (__hip_bfloat16*)(ws);
    __hip_bfloat16* act2 = (__hip_bfloat16*)(ws + szA1);
    __hip_bfloat16* act3 = (__hip_bfloat16*)(ws + szA1 + szA2);
    float* pooled        = (float*)(ws + szA1 + szA2 + szA3);
    __hip_bfloat16* W2   = (__hip_bfloat16*)(ws + szA1 + szA2 + szA3 + SZ_POOL);
    __hip_bfloat16* W3   = (__hip_bfloat16*)((char*)W2 + SZ_W2);
    __hip_bfloat16* W4   = (__hip_bfloat16*)((char*)W3 + SZ_W3);
    float* bn            = (float*)((char*)W4 + SZ_W4);

    PrepArgs pa;
    pa.w2 = w2; pa.w3 = w3; pa.w4 = w4;
    pa.g1 = (const float*)d_in[13]; pa.b1 = (const float*)d_in[14];
    pa.m1 = (const float*)d_in[15]; pa.v1 = (const float*)d_in[16];
    pa.g2 = (const float*)d_in[17]; pa.b2 = (const float*)d_in[18];
    pa.m2 = (const float*)d_in[19]; pa.v2 = (const float*)d_in[20];
    pa.g3 = (const float*)d_in[21]; pa.b3 = (const float*)d_in[22];
    pa.m3 = (const float*)d_in[23]; pa.v3 = (const float*)d_in[24];
    pa.g4 = (const float*)d_in[25]; pa.b4 = (const float*)d_in[26];
    pa.m4 = (const float*)d_in[27]; pa.v4 = (const float*)d_in[28];
    pa.W2 = W2; pa.W3 = W3; pa.W4 = W4; pa.bn = bn;

    prep_k<<<938, 256, 0, stream>>>(pa);
    for (int c = 0; c < NCHUNK; ++c) {
        int b0 = c * CH;
        deform_k<<<dim3(4, CH), 256, 0, stream>>>(x, w_off, b_off, w_dcn, b_dcn, bn,
                                                  act1, act2, act3, pooled, b0);
        conv_k<32, 64, 2, false><<<dim3(7, CH), 128, 0, stream>>>(
            act1, W2, b2, bn + 64, bn + 128, act2, nullptr, b0, CH);
        conv_k<64, 128, 4, false><<<dim3(7, CH), 256, 0, stream>>>(
            act2, W3, b3, bn + 192, bn + 320, act3, nullptr, b0, CH);
        conv_k<128, 128, 4, true><<<dim3(7, CH), 256, 0, stream>>>(
            act3, W4, b4, bn + 448, bn + 576, nullptr, pooled, b0, CH);
    }
    head_k<<<256, 256, 0, stream>>>(pooled, w_fc, b_fc, (float*)d_out);
}